// Round 1
// baseline (919.231 us; speedup 1.0000x reference)
//
#include <hip/hip_runtime.h>
#include <hip/hip_bf16.h>

// Problem constants
#define BB 2
#define TT 2048
#define DD 512
#define HH 8
#define DH 64
#define INNER 512
#define MAXLAG 5

// ---------------------------------------------------------------------------
// GEMM: C[M,N] = X[M,K] @ W[K,N] (+ bias). blockIdx.z selects one of up to 3
// (W, O) pairs so QKV runs in a single launch.
// Tiling: BM=128, BN=128, BK=16, 256 threads, 8x8 microtile per thread.
// ---------------------------------------------------------------------------
#define GBM 128
#define GBN 128
#define GBK 16

__global__ __launch_bounds__(256)
void gemm_kernel(const float* __restrict__ X,
                 const float* __restrict__ W0, const float* __restrict__ W1,
                 const float* __restrict__ W2,
                 float* __restrict__ O0, float* __restrict__ O1, float* __restrict__ O2,
                 const float* __restrict__ bias, int M, int N, int K)
{
    const float* W = (blockIdx.z == 0) ? W0 : ((blockIdx.z == 1) ? W1 : W2);
    float*       O = (blockIdx.z == 0) ? O0 : ((blockIdx.z == 1) ? O1 : O2);

    __shared__ float As[GBK][GBM + 4];  // A^T tile: As[k][m]
    __shared__ float Bs[GBK][GBN];      // B tile:  Bs[k][n]

    const int tid = threadIdx.x;
    const int tx = tid & 15;   // -> n
    const int ty = tid >> 4;   // -> m
    const int bm = blockIdx.y * GBM;
    const int bn = blockIdx.x * GBN;

    float acc[8][8];
#pragma unroll
    for (int i = 0; i < 8; ++i)
#pragma unroll
        for (int j = 0; j < 8; ++j) acc[i][j] = 0.f;

    for (int k0 = 0; k0 < K; k0 += GBK) {
        // Load A tile: 128 rows x 16 k (transposed into As[k][m])
        {
            int r  = tid >> 2;          // 0..63
            int cg = (tid & 3) * 4;     // 0,4,8,12
#pragma unroll
            for (int rr = 0; rr < GBM; rr += 64) {
                float4 a = *(const float4*)&X[(size_t)(bm + r + rr) * K + k0 + cg];
                As[cg + 0][r + rr] = a.x;
                As[cg + 1][r + rr] = a.y;
                As[cg + 2][r + rr] = a.z;
                As[cg + 3][r + rr] = a.w;
            }
        }
        // Load B tile: 16 k x 128 n
        {
            int r  = tid >> 5;          // 0..7
            int cg = (tid & 31) * 4;    // 0..124
#pragma unroll
            for (int rr = 0; rr < GBK; rr += 8) {
                float4 b = *(const float4*)&W[(size_t)(k0 + r + rr) * N + bn + cg];
                *(float4*)&Bs[r + rr][cg] = b;
            }
        }
        __syncthreads();

#pragma unroll
        for (int kk = 0; kk < GBK; ++kk) {
            float a[8], b[8];
#pragma unroll
            for (int i = 0; i < 4; ++i) {
                a[i]     = As[kk][ty * 4 + i];
                a[4 + i] = As[kk][64 + ty * 4 + i];
            }
#pragma unroll
            for (int j = 0; j < 4; ++j) {
                b[j]     = Bs[kk][tx * 4 + j];
                b[4 + j] = Bs[kk][64 + tx * 4 + j];
            }
#pragma unroll
            for (int i = 0; i < 8; ++i)
#pragma unroll
                for (int j = 0; j < 8; ++j)
                    acc[i][j] += a[i] * b[j];
        }
        __syncthreads();
    }

    // Epilogue: two float4 stores per row (cols tx*4 and 64+tx*4)
    float4 bias0 = make_float4(0.f, 0.f, 0.f, 0.f);
    float4 bias1 = make_float4(0.f, 0.f, 0.f, 0.f);
    if (bias) {
        bias0 = *(const float4*)&bias[bn + tx * 4];
        bias1 = *(const float4*)&bias[bn + 64 + tx * 4];
    }
#pragma unroll
    for (int i = 0; i < 8; ++i) {
        int m = bm + ((i < 4) ? (ty * 4 + i) : (64 + ty * 4 + (i - 4)));
        float4 v0 = make_float4(acc[i][0] + bias0.x, acc[i][1] + bias0.y,
                                acc[i][2] + bias0.z, acc[i][3] + bias0.w);
        float4 v1 = make_float4(acc[i][4] + bias1.x, acc[i][5] + bias1.y,
                                acc[i][6] + bias1.z, acc[i][7] + bias1.w);
        *(float4*)&O[(size_t)m * N + bn + tx * 4]      = v0;
        *(float4*)&O[(size_t)m * N + bn + 64 + tx * 4] = v1;
    }
}

// ---------------------------------------------------------------------------
// Flash-style causal attention with lag bias.
// One block = one (q-tile of 64 rows, b*h). 256 threads: tid = row*4 + sub,
// row in [0,64), sub in [0,4). Each thread owns S/P cols [sub*16, sub*16+16)
// and O dims [sub*16, sub*16+16).
// ---------------------------------------------------------------------------
__global__ __launch_bounds__(256)
void attn_kernel(const float* __restrict__ Qg, const float* __restrict__ Kg,
                 const float* __restrict__ Vg, const float* __restrict__ lagw,
                 float* __restrict__ Oa)
{
    __shared__ float Ks[64][68];
    __shared__ float Vs[64][68];
    __shared__ float Ps[64][68];

    const int tid = threadIdx.x;
    const int bh = blockIdx.y;
    const int b = bh >> 3;
    const int h = bh & 7;
    const int qt = blockIdx.x;
    const int i0 = qt * 64;
    const int row = tid >> 2;
    const int sub = tid & 3;
    const int i = i0 + row;   // query index
    const float scale = 0.125f;  // 64^-0.5

    // per-head lag softmax (6 values), computed redundantly per thread
    float lagp[MAXLAG + 1];
    {
        float mx = -1e30f;
#pragma unroll
        for (int l = 0; l <= MAXLAG; ++l) {
            lagp[l] = lagw[h * (MAXLAG + 1) + l];
            mx = fmaxf(mx, lagp[l]);
        }
        float s = 0.f;
#pragma unroll
        for (int l = 0; l <= MAXLAG; ++l) { lagp[l] = __expf(lagp[l] - mx); s += lagp[l]; }
        float inv = 1.f / s;
#pragma unroll
        for (int l = 0; l <= MAXLAG; ++l) lagp[l] *= inv;
    }

    // Q row in registers (64 floats)
    float qreg[64];
    {
        const float* qp = &Qg[((size_t)(b * TT + i)) * INNER + h * DH];
#pragma unroll
        for (int d = 0; d < 64; d += 4) {
            float4 t4 = *(const float4*)&qp[d];
            qreg[d] = t4.x; qreg[d + 1] = t4.y; qreg[d + 2] = t4.z; qreg[d + 3] = t4.w;
        }
    }

    float m_i = -1e30f, l_i = 0.f;
    float4 o4[4];
#pragma unroll
    for (int g = 0; g < 4; ++g) o4[g] = make_float4(0.f, 0.f, 0.f, 0.f);

    for (int kt = 0; kt <= qt; ++kt) {
        const int j0 = kt * 64;
        __syncthreads();  // prev-iteration Vs reads done before overwrite
        // load K,V tiles (64 keys x 64 dims)
        {
            int r  = tid >> 4;          // 0..15
            int dg = (tid & 15) * 4;    // 0..60
#pragma unroll
            for (int rr = 0; rr < 64; rr += 16) {
                size_t g = ((size_t)(b * TT + j0 + r + rr)) * INNER + h * DH + dg;
                *(float4*)&Ks[r + rr][dg] = *(const float4*)&Kg[g];
                *(float4*)&Vs[r + rr][dg] = *(const float4*)&Vg[g];
            }
        }
        __syncthreads();

        // S = scale * q.k + lag bias, causal mask
        float p[16];
        float mloc = -1e30f;
#pragma unroll
        for (int c = 0; c < 16; ++c) {
            const int kc = sub * 16 + c;
            float s = 0.f;
#pragma unroll
            for (int d = 0; d < 64; d += 4) {
                float4 kv = *(const float4*)&Ks[kc][d];
                s += qreg[d] * kv.x + qreg[d + 1] * kv.y + qreg[d + 2] * kv.z + qreg[d + 3] * kv.w;
            }
            const int j = j0 + kc;
            const int lag = i - j;
            if (lag < 0) {
                s = -1e30f;
            } else {
                s = s * scale + lagp[(lag > MAXLAG) ? MAXLAG : lag];
            }
            p[c] = s;
            mloc = fmaxf(mloc, s);
        }
        // row max across the 4 subs (adjacent lanes)
        mloc = fmaxf(mloc, __shfl_xor(mloc, 1));
        mloc = fmaxf(mloc, __shfl_xor(mloc, 2));
        const float m_new = fmaxf(m_i, mloc);
        const float alpha = __expf(m_i - m_new);

        float lsum = 0.f;
#pragma unroll
        for (int c = 0; c < 16; ++c) {
            p[c] = __expf(p[c] - m_new);
            lsum += p[c];
        }
        lsum += __shfl_xor(lsum, 1);
        lsum += __shfl_xor(lsum, 2);
        l_i = l_i * alpha + lsum;
        m_i = m_new;
#pragma unroll
        for (int g = 0; g < 4; ++g) {
            o4[g].x *= alpha; o4[g].y *= alpha; o4[g].z *= alpha; o4[g].w *= alpha;
        }
        // publish P tile
#pragma unroll
        for (int g = 0; g < 4; ++g) {
            *(float4*)&Ps[row][sub * 16 + g * 4] =
                make_float4(p[g * 4 + 0], p[g * 4 + 1], p[g * 4 + 2], p[g * 4 + 3]);
        }
        __syncthreads();

        // O += P @ V
#pragma unroll 8
        for (int c = 0; c < 64; ++c) {
            const float pv = Ps[row][c];
#pragma unroll
            for (int g = 0; g < 4; ++g) {
                float4 vv = *(const float4*)&Vs[c][sub * 16 + g * 4];
                o4[g].x += pv * vv.x; o4[g].y += pv * vv.y;
                o4[g].z += pv * vv.z; o4[g].w += pv * vv.w;
            }
        }
    }

    const float invl = 1.f / l_i;
    float* op = &Oa[((size_t)(b * TT + i)) * INNER + h * DH + sub * 16];
#pragma unroll
    for (int g = 0; g < 4; ++g) {
        float4 v = make_float4(o4[g].x * invl, o4[g].y * invl, o4[g].z * invl, o4[g].w * invl);
        *(float4*)&op[g * 4] = v;
    }
}

// ---------------------------------------------------------------------------
extern "C" void kernel_launch(void* const* d_in, const int* in_sizes, int n_in,
                              void* d_out, int out_size, void* d_ws, size_t ws_size,
                              hipStream_t stream)
{
    const float* x  = (const float*)d_in[0];
    const float* Wq = (const float*)d_in[1];
    const float* Wk = (const float*)d_in[2];
    const float* Wv = (const float*)d_in[3];
    const float* Wo = (const float*)d_in[4];
    const float* bo = (const float*)d_in[5];
    const float* lw = (const float*)d_in[6];
    float* out = (float*)d_out;

    const size_t SZ = (size_t)BB * TT * INNER;  // elements per activation buffer
    float* q  = (float*)d_ws;
    float* k  = q + SZ;
    float* v  = k + SZ;
    float* ao = v + SZ;

    const int M = BB * TT;  // 4096

    // QKV projection (one launch, z = 0/1/2)
    dim3 gQKV(INNER / GBN, M / GBM, 3);
    gemm_kernel<<<gQKV, 256, 0, stream>>>(x, Wq, Wk, Wv, q, k, v, nullptr, M, INNER, DD);

    // causal attention with lag bias
    dim3 gATT(TT / 64, BB * HH);
    attn_kernel<<<gATT, 256, 0, stream>>>(q, k, v, lw, ao);

    // output projection + bias
    dim3 gPRJ(DD / GBN, M / GBM, 1);
    gemm_kernel<<<gPRJ, 256, 0, stream>>>(ao, Wo, Wo, Wo, out, out, out, bo, M, DD, INNER);
}

// Round 2
// 320.711 us; speedup vs baseline: 2.8662x; 2.8662x over previous
//
#include <hip/hip_runtime.h>
#include <hip/hip_bf16.h>

// Problem constants
#define BB 2
#define TT 2048
#define DD 512
#define HH 8
#define DH 64
#define INNER 512
#define MAXLAG 5

typedef __attribute__((ext_vector_type(8))) short short8;
typedef __attribute__((ext_vector_type(4))) float floatx4;

__device__ inline unsigned short f2bf(float f) {
    unsigned u = __float_as_uint(f);
    unsigned r = (u + 0x7FFFu + ((u >> 16) & 1u)) >> 16;
    return (unsigned short)r;
}

// ---------------------------------------------------------------------------
// GEMM: C[M,N] = X[M,K] @ W[K,N] (+ bias). blockIdx.z selects (W,O) pair.
// BM=128, BN=128, BK=16, 256 threads, 8x8 microtile. OutT = float or ushort(bf16).
// ---------------------------------------------------------------------------
#define GBM 128
#define GBN 128
#define GBK 16

template <typename OutT>
__device__ inline void store4(OutT* p, float4 v);
template <>
__device__ inline void store4<float>(float* p, float4 v) { *(float4*)p = v; }
template <>
__device__ inline void store4<unsigned short>(unsigned short* p, float4 v) {
    ushort4 u;
    u.x = f2bf(v.x); u.y = f2bf(v.y); u.z = f2bf(v.z); u.w = f2bf(v.w);
    *(ushort4*)p = u;
}

template <typename OutT>
__global__ __launch_bounds__(256)
void gemm_kernel(const float* __restrict__ X,
                 const float* __restrict__ W0, const float* __restrict__ W1,
                 const float* __restrict__ W2,
                 OutT* __restrict__ O0, OutT* __restrict__ O1, OutT* __restrict__ O2,
                 const float* __restrict__ bias, int M, int N, int K)
{
    const float* W = (blockIdx.z == 0) ? W0 : ((blockIdx.z == 1) ? W1 : W2);
    OutT*        O = (blockIdx.z == 0) ? O0 : ((blockIdx.z == 1) ? O1 : O2);

    __shared__ float As[GBK][GBM + 4];
    __shared__ float Bs[GBK][GBN];

    const int tid = threadIdx.x;
    const int tx = tid & 15;
    const int ty = tid >> 4;
    const int bm = blockIdx.y * GBM;
    const int bn = blockIdx.x * GBN;

    float acc[8][8];
#pragma unroll
    for (int i = 0; i < 8; ++i)
#pragma unroll
        for (int j = 0; j < 8; ++j) acc[i][j] = 0.f;

    for (int k0 = 0; k0 < K; k0 += GBK) {
        {
            int r  = tid >> 2;
            int cg = (tid & 3) * 4;
#pragma unroll
            for (int rr = 0; rr < GBM; rr += 64) {
                float4 a = *(const float4*)&X[(size_t)(bm + r + rr) * K + k0 + cg];
                As[cg + 0][r + rr] = a.x;
                As[cg + 1][r + rr] = a.y;
                As[cg + 2][r + rr] = a.z;
                As[cg + 3][r + rr] = a.w;
            }
        }
        {
            int r  = tid >> 5;
            int cg = (tid & 31) * 4;
#pragma unroll
            for (int rr = 0; rr < GBK; rr += 8) {
                float4 b = *(const float4*)&W[(size_t)(k0 + r + rr) * N + bn + cg];
                *(float4*)&Bs[r + rr][cg] = b;
            }
        }
        __syncthreads();

#pragma unroll
        for (int kk = 0; kk < GBK; ++kk) {
            float a[8], b[8];
#pragma unroll
            for (int i = 0; i < 4; ++i) {
                a[i]     = As[kk][ty * 4 + i];
                a[4 + i] = As[kk][64 + ty * 4 + i];
            }
#pragma unroll
            for (int j = 0; j < 4; ++j) {
                b[j]     = Bs[kk][tx * 4 + j];
                b[4 + j] = Bs[kk][64 + tx * 4 + j];
            }
#pragma unroll
            for (int i = 0; i < 8; ++i)
#pragma unroll
                for (int j = 0; j < 8; ++j)
                    acc[i][j] += a[i] * b[j];
        }
        __syncthreads();
    }

    float4 bias0 = make_float4(0.f, 0.f, 0.f, 0.f);
    float4 bias1 = make_float4(0.f, 0.f, 0.f, 0.f);
    if (bias) {
        bias0 = *(const float4*)&bias[bn + tx * 4];
        bias1 = *(const float4*)&bias[bn + 64 + tx * 4];
    }
#pragma unroll
    for (int i = 0; i < 8; ++i) {
        int m = bm + ((i < 4) ? (ty * 4 + i) : (64 + ty * 4 + (i - 4)));
        float4 v0 = make_float4(acc[i][0] + bias0.x, acc[i][1] + bias0.y,
                                acc[i][2] + bias0.z, acc[i][3] + bias0.w);
        float4 v1 = make_float4(acc[i][4] + bias1.x, acc[i][5] + bias1.y,
                                acc[i][6] + bias1.z, acc[i][7] + bias1.w);
        store4<OutT>(&O[(size_t)m * N + bn + tx * 4], v0);
        store4<OutT>(&O[(size_t)m * N + bn + 64 + tx * 4], v1);
    }
}

// ---------------------------------------------------------------------------
// MFMA flash attention with lag bias. Block = 64 q-rows x (b,h); 4 waves,
// wave w owns q-rows [w*16, w*16+16). mfma_f32_16x16x32_bf16 for QK^T and PV.
// C/D layout: col = lane&15, row = (lane>>4)*4 + reg  [m89/m91 verified]
// A layout:   m = lane&15,  k = (lane>>4)*8 + j       [m120 verified]
// B layout:   n = lane&15,  k = (lane>>4)*8 + j
// LDS rows padded to 72 elems (36 words; 36 mod 32 = 4 -> worst 2-way, free).
// ---------------------------------------------------------------------------
#define PAD 72

__global__ __launch_bounds__(256)
void attn_mfma(const unsigned short* __restrict__ Qg,
               const unsigned short* __restrict__ Kg,
               const unsigned short* __restrict__ Vg,
               const float* __restrict__ lagw,
               float* __restrict__ Oa)
{
    __shared__ unsigned short Ks[64][PAD];   // [key][dim]
    __shared__ unsigned short Vt[64][PAD];   // [dim][key]   (transposed)
    __shared__ unsigned short Pl[4][16][PAD]; // per-wave P tile [row][key]

    const int tid  = threadIdx.x;
    const int wave = tid >> 6;
    const int lane = tid & 63;
    const int quad = lane >> 4;
    const int l15  = lane & 15;

    const int bh = blockIdx.y;
    const int b  = bh >> 3;
    const int h  = bh & 7;
    const int qt = (gridDim.x - 1) - blockIdx.x;  // heavy tiles dispatch first
    const int i0 = qt * 64;

    // per-head lag softmax probabilities (6 values)
    float lagp[MAXLAG + 1];
    {
        float mx = -1e30f;
#pragma unroll
        for (int l = 0; l <= MAXLAG; ++l) {
            lagp[l] = lagw[h * (MAXLAG + 1) + l];
            mx = fmaxf(mx, lagp[l]);
        }
        float s = 0.f;
#pragma unroll
        for (int l = 0; l <= MAXLAG; ++l) { lagp[l] = __expf(lagp[l] - mx); s += lagp[l]; }
        float inv = 1.f / s;
#pragma unroll
        for (int l = 0; l <= MAXLAG; ++l) lagp[l] *= inv;
    }

    // Q A-fragments, loaded once from global (row m = l15, k = quad*8+j)
    short8 qf[2];
    {
        const unsigned short* qbase =
            Qg + ((size_t)(b * TT + i0 + wave * 16 + l15)) * INNER + h * DH;
        qf[0] = *(const short8*)(qbase + quad * 8);
        qf[1] = *(const short8*)(qbase + 32 + quad * 8);
    }

    float m_i[4], l_i[4];
    floatx4 oacc[4];
#pragma unroll
    for (int r = 0; r < 4; ++r) { m_i[r] = -1e30f; l_i[r] = 0.f; }
#pragma unroll
    for (int cb = 0; cb < 4; ++cb) oacc[cb] = (floatx4){0.f, 0.f, 0.f, 0.f};

    const int ibase = i0 + wave * 16 + quad * 4;  // + reg = query index
    const float scale = 0.125f;

    for (int kt = 0; kt <= qt; ++kt) {
        const int j0 = kt * 64;
        __syncthreads();  // protect Ks/Vt from previous iteration's readers
        {
            const int key = tid >> 2;
            const int dg  = (tid & 3) * 16;
            const unsigned short* kp =
                Kg + ((size_t)(b * TT + j0 + key)) * INNER + h * DH + dg;
            const unsigned short* vp =
                Vg + ((size_t)(b * TT + j0 + key)) * INNER + h * DH + dg;
            uint4 k0v = *(const uint4*)kp;
            uint4 k1v = *(const uint4*)(kp + 8);
            *(uint4*)&Ks[key][dg]     = k0v;
            *(uint4*)&Ks[key][dg + 8] = k1v;
            unsigned short vv[16];
            *(uint4*)&vv[0] = *(const uint4*)vp;
            *(uint4*)&vv[8] = *(const uint4*)(vp + 8);
#pragma unroll
            for (int j = 0; j < 16; ++j) Vt[dg + j][key] = vv[j];
        }
        __syncthreads();

        // S = Q @ K^T (16x64 per wave, 4 col-blocks)
        floatx4 sacc[4];
#pragma unroll
        for (int cb = 0; cb < 4; ++cb) {
            short8 kf0 = *(const short8*)&Ks[cb * 16 + l15][quad * 8];
            short8 kf1 = *(const short8*)&Ks[cb * 16 + l15][32 + quad * 8];
            floatx4 z = (floatx4){0.f, 0.f, 0.f, 0.f};
            z = __builtin_amdgcn_mfma_f32_16x16x32_bf16(qf[0], kf0, z, 0, 0, 0);
            z = __builtin_amdgcn_mfma_f32_16x16x32_bf16(qf[1], kf1, z, 0, 0, 0);
            sacc[cb] = z;
        }

        // mask + lag bias + online softmax
        float p[4][4];
        float mloc[4] = {-1e30f, -1e30f, -1e30f, -1e30f};
#pragma unroll
        for (int cb = 0; cb < 4; ++cb) {
            const int j = j0 + cb * 16 + l15;
#pragma unroll
            for (int reg = 0; reg < 4; ++reg) {
                const int lag = (ibase + reg) - j;
                float s;
                if (lag < 0) s = -1e30f;
                else         s = sacc[cb][reg] * scale + lagp[(lag > MAXLAG) ? MAXLAG : lag];
                p[cb][reg] = s;
                mloc[reg] = fmaxf(mloc[reg], s);
            }
        }
#pragma unroll
        for (int reg = 0; reg < 4; ++reg) {
            mloc[reg] = fmaxf(mloc[reg], __shfl_xor(mloc[reg], 1));
            mloc[reg] = fmaxf(mloc[reg], __shfl_xor(mloc[reg], 2));
            mloc[reg] = fmaxf(mloc[reg], __shfl_xor(mloc[reg], 4));
            mloc[reg] = fmaxf(mloc[reg], __shfl_xor(mloc[reg], 8));
        }
        float alpha[4], ls[4];
#pragma unroll
        for (int reg = 0; reg < 4; ++reg) {
            const float mnew = fmaxf(m_i[reg], mloc[reg]);
            alpha[reg] = __expf(m_i[reg] - mnew);
            m_i[reg] = mnew;
            ls[reg] = 0.f;
        }
#pragma unroll
        for (int cb = 0; cb < 4; ++cb)
#pragma unroll
            for (int reg = 0; reg < 4; ++reg) {
                float e = __expf(p[cb][reg] - m_i[reg]);
                p[cb][reg] = e;
                ls[reg] += e;
            }
#pragma unroll
        for (int reg = 0; reg < 4; ++reg) {
            ls[reg] += __shfl_xor(ls[reg], 1);
            ls[reg] += __shfl_xor(ls[reg], 2);
            ls[reg] += __shfl_xor(ls[reg], 4);
            ls[reg] += __shfl_xor(ls[reg], 8);
            l_i[reg] = l_i[reg] * alpha[reg] + ls[reg];
        }
#pragma unroll
        for (int cb = 0; cb < 4; ++cb)
#pragma unroll
            for (int reg = 0; reg < 4; ++reg)
                oacc[cb][reg] *= alpha[reg];

        // P: C-layout -> LDS -> A-layout (wave-private tile, no barrier needed)
#pragma unroll
        for (int cb = 0; cb < 4; ++cb)
#pragma unroll
            for (int reg = 0; reg < 4; ++reg)
                Pl[wave][quad * 4 + reg][cb * 16 + l15] = f2bf(p[cb][reg]);

        short8 pf0 = *(const short8*)&Pl[wave][l15][quad * 8];
        short8 pf1 = *(const short8*)&Pl[wave][l15][32 + quad * 8];

        // O += P @ V  (V in Vt[dim][key]: B-frag is contiguous 16B)
#pragma unroll
        for (int cb = 0; cb < 4; ++cb) {
            short8 vf0 = *(const short8*)&Vt[cb * 16 + l15][quad * 8];
            short8 vf1 = *(const short8*)&Vt[cb * 16 + l15][32 + quad * 8];
            oacc[cb] = __builtin_amdgcn_mfma_f32_16x16x32_bf16(pf0, vf0, oacc[cb], 0, 0, 0);
            oacc[cb] = __builtin_amdgcn_mfma_f32_16x16x32_bf16(pf1, vf1, oacc[cb], 0, 0, 0);
        }
    }

    // epilogue: normalize and store fp32
#pragma unroll
    for (int reg = 0; reg < 4; ++reg) {
        const float invl = 1.f / l_i[reg];
        const size_t base = ((size_t)(b * TT + ibase + reg)) * INNER + h * DH;
#pragma unroll
        for (int cb = 0; cb < 4; ++cb)
            Oa[base + cb * 16 + l15] = oacc[cb][reg] * invl;
    }
}

// ---------------------------------------------------------------------------
extern "C" void kernel_launch(void* const* d_in, const int* in_sizes, int n_in,
                              void* d_out, int out_size, void* d_ws, size_t ws_size,
                              hipStream_t stream)
{
    const float* x  = (const float*)d_in[0];
    const float* Wq = (const float*)d_in[1];
    const float* Wk = (const float*)d_in[2];
    const float* Wv = (const float*)d_in[3];
    const float* Wo = (const float*)d_in[4];
    const float* bo = (const float*)d_in[5];
    const float* lw = (const float*)d_in[6];
    float* out = (float*)d_out;

    const size_t SZ = (size_t)BB * TT * INNER;
    unsigned short* q = (unsigned short*)d_ws;           // bf16
    unsigned short* k = q + SZ;                          // bf16
    unsigned short* v = k + SZ;                          // bf16
    float* ao = (float*)(v + SZ);                        // fp32

    const int M = BB * TT;  // 4096

    // QKV projection -> bf16 outputs
    dim3 gQKV(INNER / GBN, M / GBM, 3);
    gemm_kernel<unsigned short><<<gQKV, 256, 0, stream>>>(
        x, Wq, Wk, Wv, q, k, v, nullptr, M, INNER, DD);

    // MFMA flash attention with lag bias
    dim3 gATT(TT / 64, BB * HH);
    attn_mfma<<<gATT, 256, 0, stream>>>(q, k, v, lw, ao);

    // output projection + bias (fp32)
    dim3 gPRJ(DD / GBN, M / GBM, 1);
    gemm_kernel<float><<<gPRJ, 256, 0, stream>>>(
        ao, Wo, Wo, Wo, out, out, out, bo, M, DD, INNER);
}

// Round 3
// 209.841 us; speedup vs baseline: 4.3806x; 1.5283x over previous
//
#include <hip/hip_runtime.h>
#include <hip/hip_bf16.h>

// Problem constants
#define BB 2
#define TT 2048
#define DD 512
#define HH 8
#define DH 64
#define INNER 512
#define MAXLAG 5

typedef __attribute__((ext_vector_type(8))) short short8;
typedef __attribute__((ext_vector_type(4))) float floatx4;
typedef unsigned short ushort_t;

__device__ inline unsigned short f2bf(float f) {
    unsigned u = __float_as_uint(f);
    unsigned r = (u + 0x7FFFu + ((u >> 16) & 1u)) >> 16;
    return (unsigned short)r;
}

// ---------------------------------------------------------------------------
// Convert pre-pass: x -> bf16 (straight), four 512x512 weights -> bf16
// TRANSPOSED (Wt[n*512+k] = W[k*512+n]) so GEMM B-tiles stage like A-tiles.
// ---------------------------------------------------------------------------
#define NXE (BB * TT * DD)   // 2097152
#define NWE (DD * INNER)     // 262144 per weight
#define UX (NXE / 8)         // 262144 units
#define UW (NWE / 8)         // 32768 units
#define CVT_UNITS (UX + 4 * UW)  // 393216

__global__ __launch_bounds__(256)
void cvt_kernel(const float* __restrict__ x,
                const float* __restrict__ wq, const float* __restrict__ wk,
                const float* __restrict__ wv, const float* __restrict__ wo,
                ushort_t* __restrict__ xb,
                ushort_t* __restrict__ wqt, ushort_t* __restrict__ wkt,
                ushort_t* __restrict__ wvt, ushort_t* __restrict__ wot)
{
    int u = blockIdx.x * 256 + threadIdx.x;
    if (u >= CVT_UNITS) return;
    if (u < UX) {
        int off = u * 8;
        float4 a = *(const float4*)&x[off];
        float4 b = *(const float4*)&x[off + 4];
        ushort_t t[8];
        t[0] = f2bf(a.x); t[1] = f2bf(a.y); t[2] = f2bf(a.z); t[3] = f2bf(a.w);
        t[4] = f2bf(b.x); t[5] = f2bf(b.y); t[6] = f2bf(b.z); t[7] = f2bf(b.w);
        *(uint4*)&xb[off] = *(const uint4*)t;
    } else {
        u -= UX;
        const int wi = u / UW;
        const int r  = u % UW;
        const float* s = (wi == 0) ? wq : (wi == 1) ? wk : (wi == 2) ? wv : wo;
        ushort_t*    d = (wi == 0) ? wqt : (wi == 1) ? wkt : (wi == 2) ? wvt : wot;
        const int n  = r >> 6;          // output row (0..511)
        const int kb = (r & 63) * 8;    // output col base
        ushort_t t[8];
#pragma unroll
        for (int j = 0; j < 8; ++j) t[j] = f2bf(s[(size_t)(kb + j) * 512 + n]);
        *(uint4*)&d[(size_t)n * 512 + kb] = *(const uint4*)t;
    }
}

// ---------------------------------------------------------------------------
// bf16 MFMA GEMM: C[M,N] = A[M,K] @ B^T[N,K] (+bias). A, B both bf16; B is
// pre-transposed so both tiles stage identically. 128x128x32 tile, 4 waves
// (2x2), each wave 64x64 via 4x4 grid of 16x16x32 MFMAs.
// LDS rows padded to 34 elems (17 words, odd stride -> conflicts bounded).
// blockIdx.z selects (B, O) pair for fused QKV.
// ---------------------------------------------------------------------------
#define TBM 128
#define TBN 128
#define TBK 32
#define LDK 34

template <typename OutT>
__global__ __launch_bounds__(256)
void gemm_mfma(const ushort_t* __restrict__ A,
               const ushort_t* __restrict__ B0, const ushort_t* __restrict__ B1,
               const ushort_t* __restrict__ B2,
               OutT* __restrict__ O0, OutT* __restrict__ O1, OutT* __restrict__ O2,
               const float* __restrict__ bias, int M, int N, int K)
{
    const ushort_t* Bw = (blockIdx.z == 0) ? B0 : ((blockIdx.z == 1) ? B1 : B2);
    OutT*           O  = (blockIdx.z == 0) ? O0 : ((blockIdx.z == 1) ? O1 : O2);

    __shared__ ushort_t As[TBM][LDK];
    __shared__ ushort_t Bs[TBN][LDK];

    const int tid  = threadIdx.x;
    const int wave = tid >> 6;
    const int lane = tid & 63;
    const int quad = lane >> 4;
    const int l15  = lane & 15;
    const int wr   = wave >> 1;
    const int wc   = wave & 1;
    const int bm   = blockIdx.y * TBM;
    const int bn   = blockIdx.x * TBN;

    floatx4 acc[4][4];
#pragma unroll
    for (int i = 0; i < 4; ++i)
#pragma unroll
        for (int j = 0; j < 4; ++j) acc[i][j] = (floatx4){0.f, 0.f, 0.f, 0.f};

    const int r2 = tid >> 1;          // 0..127
    const int c2 = (tid & 1) * 16;    // 0 or 16

    for (int k0 = 0; k0 < K; k0 += TBK) {
        __syncthreads();
        {
            const ushort_t* ap = &A[(size_t)(bm + r2) * K + k0 + c2];
            uint4 a0 = *(const uint4*)ap;
            uint4 a1 = *(const uint4*)(ap + 8);
            const ushort_t* bp = &Bw[(size_t)(bn + r2) * K + k0 + c2];
            uint4 b0 = *(const uint4*)bp;
            uint4 b1 = *(const uint4*)(bp + 8);
            *(uint4*)&As[r2][c2]     = a0;
            *(uint4*)&As[r2][c2 + 8] = a1;
            *(uint4*)&Bs[r2][c2]     = b0;
            *(uint4*)&Bs[r2][c2 + 8] = b1;
        }
        __syncthreads();

        short8 af[4], bf[4];
#pragma unroll
        for (int mt = 0; mt < 4; ++mt)
            af[mt] = *(const short8*)&As[wr * 64 + mt * 16 + l15][quad * 8];
#pragma unroll
        for (int nt = 0; nt < 4; ++nt)
            bf[nt] = *(const short8*)&Bs[wc * 64 + nt * 16 + l15][quad * 8];
#pragma unroll
        for (int mt = 0; mt < 4; ++mt)
#pragma unroll
            for (int nt = 0; nt < 4; ++nt)
                acc[mt][nt] = __builtin_amdgcn_mfma_f32_16x16x32_bf16(
                    af[mt], bf[nt], acc[mt][nt], 0, 0, 0);
    }

    // epilogue
    float bv[4] = {0.f, 0.f, 0.f, 0.f};
    if (bias) {
#pragma unroll
        for (int nt = 0; nt < 4; ++nt)
            bv[nt] = bias[bn + wc * 64 + nt * 16 + l15];
    }
#pragma unroll
    for (int mt = 0; mt < 4; ++mt) {
#pragma unroll
        for (int nt = 0; nt < 4; ++nt) {
            const int n = bn + wc * 64 + nt * 16 + l15;
#pragma unroll
            for (int reg = 0; reg < 4; ++reg) {
                const int m = bm + wr * 64 + mt * 16 + quad * 4 + reg;
                float v = acc[mt][nt][reg] + bv[nt];
                if constexpr (sizeof(OutT) == 2)
                    O[(size_t)m * N + n] = (OutT)f2bf(v);
                else
                    O[(size_t)m * N + n] = (OutT)v;
            }
        }
    }
}

// ---------------------------------------------------------------------------
// MFMA flash attention with lag bias (unchanged from R2 except bf16 output).
// ---------------------------------------------------------------------------
#define PAD 72

__global__ __launch_bounds__(256)
void attn_mfma(const ushort_t* __restrict__ Qg,
               const ushort_t* __restrict__ Kg,
               const ushort_t* __restrict__ Vg,
               const float* __restrict__ lagw,
               ushort_t* __restrict__ Oa)
{
    __shared__ ushort_t Ks[64][PAD];    // [key][dim]
    __shared__ ushort_t Vt[64][PAD];    // [dim][key]
    __shared__ ushort_t Pl[4][16][PAD]; // per-wave P tile

    const int tid  = threadIdx.x;
    const int wave = tid >> 6;
    const int lane = tid & 63;
    const int quad = lane >> 4;
    const int l15  = lane & 15;

    const int bh = blockIdx.y;
    const int b  = bh >> 3;
    const int h  = bh & 7;
    const int qt = (gridDim.x - 1) - blockIdx.x;
    const int i0 = qt * 64;

    float lagp[MAXLAG + 1];
    {
        float mx = -1e30f;
#pragma unroll
        for (int l = 0; l <= MAXLAG; ++l) {
            lagp[l] = lagw[h * (MAXLAG + 1) + l];
            mx = fmaxf(mx, lagp[l]);
        }
        float s = 0.f;
#pragma unroll
        for (int l = 0; l <= MAXLAG; ++l) { lagp[l] = __expf(lagp[l] - mx); s += lagp[l]; }
        float inv = 1.f / s;
#pragma unroll
        for (int l = 0; l <= MAXLAG; ++l) lagp[l] *= inv;
    }

    short8 qf[2];
    {
        const ushort_t* qbase =
            Qg + ((size_t)(b * TT + i0 + wave * 16 + l15)) * INNER + h * DH;
        qf[0] = *(const short8*)(qbase + quad * 8);
        qf[1] = *(const short8*)(qbase + 32 + quad * 8);
    }

    float m_i[4], l_i[4];
    floatx4 oacc[4];
#pragma unroll
    for (int r = 0; r < 4; ++r) { m_i[r] = -1e30f; l_i[r] = 0.f; }
#pragma unroll
    for (int cb = 0; cb < 4; ++cb) oacc[cb] = (floatx4){0.f, 0.f, 0.f, 0.f};

    const int ibase = i0 + wave * 16 + quad * 4;
    const float scale = 0.125f;

    for (int kt = 0; kt <= qt; ++kt) {
        const int j0 = kt * 64;
        __syncthreads();
        {
            const int key = tid >> 2;
            const int dg  = (tid & 3) * 16;
            const ushort_t* kp = Kg + ((size_t)(b * TT + j0 + key)) * INNER + h * DH + dg;
            const ushort_t* vp = Vg + ((size_t)(b * TT + j0 + key)) * INNER + h * DH + dg;
            uint4 k0v = *(const uint4*)kp;
            uint4 k1v = *(const uint4*)(kp + 8);
            *(uint4*)&Ks[key][dg]     = k0v;
            *(uint4*)&Ks[key][dg + 8] = k1v;
            ushort_t vv[16];
            *(uint4*)&vv[0] = *(const uint4*)vp;
            *(uint4*)&vv[8] = *(const uint4*)(vp + 8);
#pragma unroll
            for (int j = 0; j < 16; ++j) Vt[dg + j][key] = vv[j];
        }
        __syncthreads();

        floatx4 sacc[4];
#pragma unroll
        for (int cb = 0; cb < 4; ++cb) {
            short8 kf0 = *(const short8*)&Ks[cb * 16 + l15][quad * 8];
            short8 kf1 = *(const short8*)&Ks[cb * 16 + l15][32 + quad * 8];
            floatx4 z = (floatx4){0.f, 0.f, 0.f, 0.f};
            z = __builtin_amdgcn_mfma_f32_16x16x32_bf16(qf[0], kf0, z, 0, 0, 0);
            z = __builtin_amdgcn_mfma_f32_16x16x32_bf16(qf[1], kf1, z, 0, 0, 0);
            sacc[cb] = z;
        }

        float p[4][4];
        float mloc[4] = {-1e30f, -1e30f, -1e30f, -1e30f};
#pragma unroll
        for (int cb = 0; cb < 4; ++cb) {
            const int j = j0 + cb * 16 + l15;
#pragma unroll
            for (int reg = 0; reg < 4; ++reg) {
                const int lag = (ibase + reg) - j;
                float s;
                if (lag < 0) s = -1e30f;
                else         s = sacc[cb][reg] * scale + lagp[(lag > MAXLAG) ? MAXLAG : lag];
                p[cb][reg] = s;
                mloc[reg] = fmaxf(mloc[reg], s);
            }
        }
#pragma unroll
        for (int reg = 0; reg < 4; ++reg) {
            mloc[reg] = fmaxf(mloc[reg], __shfl_xor(mloc[reg], 1));
            mloc[reg] = fmaxf(mloc[reg], __shfl_xor(mloc[reg], 2));
            mloc[reg] = fmaxf(mloc[reg], __shfl_xor(mloc[reg], 4));
            mloc[reg] = fmaxf(mloc[reg], __shfl_xor(mloc[reg], 8));
        }
        float alpha[4], ls[4];
#pragma unroll
        for (int reg = 0; reg < 4; ++reg) {
            const float mnew = fmaxf(m_i[reg], mloc[reg]);
            alpha[reg] = __expf(m_i[reg] - mnew);
            m_i[reg] = mnew;
            ls[reg] = 0.f;
        }
#pragma unroll
        for (int cb = 0; cb < 4; ++cb)
#pragma unroll
            for (int reg = 0; reg < 4; ++reg) {
                float e = __expf(p[cb][reg] - m_i[reg]);
                p[cb][reg] = e;
                ls[reg] += e;
            }
#pragma unroll
        for (int reg = 0; reg < 4; ++reg) {
            ls[reg] += __shfl_xor(ls[reg], 1);
            ls[reg] += __shfl_xor(ls[reg], 2);
            ls[reg] += __shfl_xor(ls[reg], 4);
            ls[reg] += __shfl_xor(ls[reg], 8);
            l_i[reg] = l_i[reg] * alpha[reg] + ls[reg];
        }
#pragma unroll
        for (int cb = 0; cb < 4; ++cb)
#pragma unroll
            for (int reg = 0; reg < 4; ++reg)
                oacc[cb][reg] *= alpha[reg];

#pragma unroll
        for (int cb = 0; cb < 4; ++cb)
#pragma unroll
            for (int reg = 0; reg < 4; ++reg)
                Pl[wave][quad * 4 + reg][cb * 16 + l15] = f2bf(p[cb][reg]);

        short8 pf0 = *(const short8*)&Pl[wave][l15][quad * 8];
        short8 pf1 = *(const short8*)&Pl[wave][l15][32 + quad * 8];

#pragma unroll
        for (int cb = 0; cb < 4; ++cb) {
            short8 vf0 = *(const short8*)&Vt[cb * 16 + l15][quad * 8];
            short8 vf1 = *(const short8*)&Vt[cb * 16 + l15][32 + quad * 8];
            oacc[cb] = __builtin_amdgcn_mfma_f32_16x16x32_bf16(pf0, vf0, oacc[cb], 0, 0, 0);
            oacc[cb] = __builtin_amdgcn_mfma_f32_16x16x32_bf16(pf1, vf1, oacc[cb], 0, 0, 0);
        }
    }

#pragma unroll
    for (int reg = 0; reg < 4; ++reg) {
        const float invl = 1.f / l_i[reg];
        const size_t base = ((size_t)(b * TT + ibase + reg)) * INNER + h * DH;
#pragma unroll
        for (int cb = 0; cb < 4; ++cb)
            Oa[base + cb * 16 + l15] = f2bf(oacc[cb][reg] * invl);
    }
}

// ---------------------------------------------------------------------------
extern "C" void kernel_launch(void* const* d_in, const int* in_sizes, int n_in,
                              void* d_out, int out_size, void* d_ws, size_t ws_size,
                              hipStream_t stream)
{
    const float* x  = (const float*)d_in[0];
    const float* Wq = (const float*)d_in[1];
    const float* Wk = (const float*)d_in[2];
    const float* Wv = (const float*)d_in[3];
    const float* Wo = (const float*)d_in[4];
    const float* bo = (const float*)d_in[5];
    const float* lw = (const float*)d_in[6];
    float* out = (float*)d_out;

    const size_t SZ = (size_t)BB * TT * INNER;  // 2M elements
    ushort_t* xb  = (ushort_t*)d_ws;            // [M][D] bf16 (reused as ao)
    ushort_t* wqt = xb + SZ;                    // [N][K] bf16, transposed
    ushort_t* wkt = wqt + NWE;
    ushort_t* wvt = wkt + NWE;
    ushort_t* wot = wvt + NWE;
    ushort_t* q   = wot + NWE;
    ushort_t* k   = q + SZ;
    ushort_t* v   = k + SZ;
    ushort_t* ao  = xb;                          // alias: xb dead after QKV gemm

    const int M = BB * TT;  // 4096

    // 1) convert x + weights (weights transposed)
    cvt_kernel<<<CVT_UNITS / 256, 256, 0, stream>>>(
        x, Wq, Wk, Wv, Wo, xb, wqt, wkt, wvt, wot);

    // 2) QKV projection (bf16 MFMA, fused z=0/1/2)
    dim3 gQKV(INNER / TBN, M / TBM, 3);
    gemm_mfma<ushort_t><<<gQKV, 256, 0, stream>>>(
        xb, wqt, wkt, wvt, q, k, v, nullptr, M, INNER, DD);

    // 3) MFMA flash attention with lag bias -> bf16 ao
    dim3 gATT(TT / 64, BB * HH);
    attn_mfma<<<gATT, 256, 0, stream>>>(q, k, v, lw, ao);

    // 4) output projection + bias (fp32 out)
    dim3 gPRJ(DD / TBN, M / TBM, 1);
    gemm_mfma<float><<<gPRJ, 256, 0, stream>>>(
        ao, wot, wot, wot, out, out, out, bo, M, DD, INNER);
}

// Round 4
// 160.840 us; speedup vs baseline: 5.7152x; 1.3047x over previous
//
#include <hip/hip_runtime.h>
#include <hip/hip_bf16.h>

// Problem constants
#define BB 2
#define TT 2048
#define DD 512
#define HH 8
#define DH 64
#define INNER 512
#define MAXLAG 5

typedef __attribute__((ext_vector_type(8))) short short8;
typedef __attribute__((ext_vector_type(4))) float floatx4;
typedef unsigned short ushort_t;

__device__ inline unsigned short f2bf(float f) {
    unsigned u = __float_as_uint(f);
    unsigned r = (u + 0x7FFFu + ((u >> 16) & 1u)) >> 16;
    return (unsigned short)r;
}
__device__ inline float bf2f(unsigned short u) {
    return __uint_as_float(((unsigned)u) << 16);
}

// ---------------------------------------------------------------------------
// Convert pre-pass: x -> bf16, four 512x512 weights -> bf16 TRANSPOSED.
// ---------------------------------------------------------------------------
#define NXE (BB * TT * DD)
#define NWE (DD * INNER)
#define UX (NXE / 8)
#define UW (NWE / 8)
#define CVT_UNITS (UX + 4 * UW)

__global__ __launch_bounds__(256)
void cvt_kernel(const float* __restrict__ x,
                const float* __restrict__ wq, const float* __restrict__ wk,
                const float* __restrict__ wv, const float* __restrict__ wo,
                ushort_t* __restrict__ xb,
                ushort_t* __restrict__ wqt, ushort_t* __restrict__ wkt,
                ushort_t* __restrict__ wvt, ushort_t* __restrict__ wot)
{
    int u = blockIdx.x * 256 + threadIdx.x;
    if (u >= CVT_UNITS) return;
    if (u < UX) {
        int off = u * 8;
        float4 a = *(const float4*)&x[off];
        float4 b = *(const float4*)&x[off + 4];
        ushort_t t[8];
        t[0] = f2bf(a.x); t[1] = f2bf(a.y); t[2] = f2bf(a.z); t[3] = f2bf(a.w);
        t[4] = f2bf(b.x); t[5] = f2bf(b.y); t[6] = f2bf(b.z); t[7] = f2bf(b.w);
        *(uint4*)&xb[off] = *(const uint4*)t;
    } else {
        u -= UX;
        const int wi = u / UW;
        const int r  = u % UW;
        const float* s = (wi == 0) ? wq : (wi == 1) ? wk : (wi == 2) ? wv : wo;
        ushort_t*    d = (wi == 0) ? wqt : (wi == 1) ? wkt : (wi == 2) ? wvt : wot;
        const int n  = r >> 6;
        const int kb = (r & 63) * 8;
        ushort_t t[8];
#pragma unroll
        for (int j = 0; j < 8; ++j) t[j] = f2bf(s[(size_t)(kb + j) * 512 + n]);
        *(uint4*)&d[(size_t)n * 512 + kb] = *(const uint4*)t;
    }
}

// ---------------------------------------------------------------------------
// bf16 MFMA GEMM (unchanged from R3): C = A @ B^T (+bias), 128x128x32.
// ---------------------------------------------------------------------------
#define TBM 128
#define TBN 128
#define TBK 32
#define LDK 34

template <typename OutT>
__global__ __launch_bounds__(256)
void gemm_mfma(const ushort_t* __restrict__ A,
               const ushort_t* __restrict__ B0, const ushort_t* __restrict__ B1,
               const ushort_t* __restrict__ B2,
               OutT* __restrict__ O0, OutT* __restrict__ O1, OutT* __restrict__ O2,
               const float* __restrict__ bias, int M, int N, int K)
{
    const ushort_t* Bw = (blockIdx.z == 0) ? B0 : ((blockIdx.z == 1) ? B1 : B2);
    OutT*           O  = (blockIdx.z == 0) ? O0 : ((blockIdx.z == 1) ? O1 : O2);

    __shared__ ushort_t As[TBM][LDK];
    __shared__ ushort_t Bs[TBN][LDK];

    const int tid  = threadIdx.x;
    const int wave = tid >> 6;
    const int lane = tid & 63;
    const int quad = lane >> 4;
    const int l15  = lane & 15;
    const int wr   = wave >> 1;
    const int wc   = wave & 1;
    const int bm   = blockIdx.y * TBM;
    const int bn   = blockIdx.x * TBN;

    floatx4 acc[4][4];
#pragma unroll
    for (int i = 0; i < 4; ++i)
#pragma unroll
        for (int j = 0; j < 4; ++j) acc[i][j] = (floatx4){0.f, 0.f, 0.f, 0.f};

    const int r2 = tid >> 1;
    const int c2 = (tid & 1) * 16;

    for (int k0 = 0; k0 < K; k0 += TBK) {
        __syncthreads();
        {
            const ushort_t* ap = &A[(size_t)(bm + r2) * K + k0 + c2];
            uint4 a0 = *(const uint4*)ap;
            uint4 a1 = *(const uint4*)(ap + 8);
            const ushort_t* bp = &Bw[(size_t)(bn + r2) * K + k0 + c2];
            uint4 b0 = *(const uint4*)bp;
            uint4 b1 = *(const uint4*)(bp + 8);
            *(uint4*)&As[r2][c2]     = a0;
            *(uint4*)&As[r2][c2 + 8] = a1;
            *(uint4*)&Bs[r2][c2]     = b0;
            *(uint4*)&Bs[r2][c2 + 8] = b1;
        }
        __syncthreads();

        short8 af[4], bf[4];
#pragma unroll
        for (int mt = 0; mt < 4; ++mt)
            af[mt] = *(const short8*)&As[wr * 64 + mt * 16 + l15][quad * 8];
#pragma unroll
        for (int nt = 0; nt < 4; ++nt)
            bf[nt] = *(const short8*)&Bs[wc * 64 + nt * 16 + l15][quad * 8];
#pragma unroll
        for (int mt = 0; mt < 4; ++mt)
#pragma unroll
            for (int nt = 0; nt < 4; ++nt)
                acc[mt][nt] = __builtin_amdgcn_mfma_f32_16x16x32_bf16(
                    af[mt], bf[nt], acc[mt][nt], 0, 0, 0);
    }

    float bv[4] = {0.f, 0.f, 0.f, 0.f};
    if (bias) {
#pragma unroll
        for (int nt = 0; nt < 4; ++nt)
            bv[nt] = bias[bn + wc * 64 + nt * 16 + l15];
    }
#pragma unroll
    for (int mt = 0; mt < 4; ++mt) {
#pragma unroll
        for (int nt = 0; nt < 4; ++nt) {
            const int n = bn + wc * 64 + nt * 16 + l15;
#pragma unroll
            for (int reg = 0; reg < 4; ++reg) {
                const int m = bm + wr * 64 + mt * 16 + quad * 4 + reg;
                float v = acc[mt][nt][reg] + bv[nt];
                if constexpr (sizeof(OutT) == 2)
                    O[(size_t)m * N + n] = (OutT)f2bf(v);
                else
                    O[(size_t)m * N + n] = (OutT)v;
            }
        }
    }
}

// ---------------------------------------------------------------------------
// MFMA flash attention, K-split x2, fixed-max softmax, register prefetch.
// Chunk c: qt = 31 - (c>>1), s = c&1; kt range [lo,hi) is the s-th half of
// [0, qt+1). Partials: Opart[s][bh][i][d] bf16 (unnormalized), Lpart fp32.
// Vt stored XOR-swizzled in 8-key chunks: chunk' = (key>>3) ^ ((d>>3)&7)
// -> staging writes spread over all 32 banks (2-way = free).
// MFIX=10: logits s*0.125+lagp bounded << 10+88, so no online max needed.
// ---------------------------------------------------------------------------
#define PAD 72
#define MFIX 10.0f

__global__ __launch_bounds__(256)
void attn_mfma(const ushort_t* __restrict__ Qg,
               const ushort_t* __restrict__ Kg,
               const ushort_t* __restrict__ Vg,
               const float* __restrict__ lagw,
               ushort_t* __restrict__ Opart,
               float* __restrict__ Lpart)
{
    __shared__ ushort_t Ks[64][PAD];
    __shared__ ushort_t Vt[64][PAD];
    __shared__ ushort_t Pl[4][16][PAD];

    const int tid  = threadIdx.x;
    const int wave = tid >> 6;
    const int lane = tid & 63;
    const int quad = lane >> 4;
    const int l15  = lane & 15;

    const int bh = blockIdx.y;
    const int b  = bh >> 3;
    const int h  = bh & 7;
    const int c  = blockIdx.x;         // 0..63, heavy qt first
    const int qt = 31 - (c >> 1);
    const int sp = c & 1;
    const int i0 = qt * 64;
    const int h1 = (qt + 1) >> 1;
    const int lo = sp ? h1 : 0;
    const int hi = sp ? (qt + 1) : h1;

    // lag softmax probs minus MFIX (bias folded into exp argument)
    float lagb[MAXLAG + 1];
    {
        float mx = -1e30f;
#pragma unroll
        for (int l = 0; l <= MAXLAG; ++l) {
            lagb[l] = lagw[h * (MAXLAG + 1) + l];
            mx = fmaxf(mx, lagb[l]);
        }
        float s = 0.f;
#pragma unroll
        for (int l = 0; l <= MAXLAG; ++l) { lagb[l] = __expf(lagb[l] - mx); s += lagb[l]; }
        float inv = 1.f / s;
#pragma unroll
        for (int l = 0; l <= MAXLAG; ++l) lagb[l] = lagb[l] * inv - MFIX;
    }
    const float c1  = 0.125f;       // 1/sqrt(64)
    const float c2f = lagb[MAXLAG]; // fast-path bias (all lags >= MAXLAG)

    // Q A-fragments
    short8 qf0, qf1;
    {
        const ushort_t* qbase =
            Qg + ((size_t)(b * TT + i0 + wave * 16 + l15)) * INNER + h * DH;
        qf0 = *(const short8*)(qbase + quad * 8);
        qf1 = *(const short8*)(qbase + 32 + quad * 8);
    }

    floatx4 oacc[4];
    float lsum[4] = {0.f, 0.f, 0.f, 0.f};
#pragma unroll
    for (int cb = 0; cb < 4; ++cb) oacc[cb] = (floatx4){0.f, 0.f, 0.f, 0.f};

    const int ibase = i0 + wave * 16 + quad * 4;
    const int key = tid >> 2;
    const int dg  = (tid & 3) * 16;
    const ushort_t* Kbase = Kg + ((size_t)b * TT) * INNER + h * DH + dg;
    const ushort_t* Vbase = Vg + ((size_t)b * TT) * INNER + h * DH + dg;

    uint4 pk0, pk1, pv0, pv1;
    if (lo < hi) {
        size_t off = (size_t)(lo * 64 + key) * INNER;
        pk0 = *(const uint4*)(Kbase + off);
        pk1 = *(const uint4*)(Kbase + off + 8);
        pv0 = *(const uint4*)(Vbase + off);
        pv1 = *(const uint4*)(Vbase + off + 8);
    }

    for (int kt = lo; kt < hi; ++kt) {
        __syncthreads();   // previous iteration's LDS readers done
        // commit staged tile to LDS
        *(uint4*)&Ks[key][dg]     = pk0;
        *(uint4*)&Ks[key][dg + 8] = pk1;
        {
            ushort_t vv[16];
            *(uint4*)&vv[0] = pv0;
            *(uint4*)&vv[8] = pv1;
            const int kc = key >> 3, kl = key & 7;
#pragma unroll
            for (int j = 0; j < 16; ++j) {
                const int d = dg + j;
                Vt[d][((kc ^ ((d >> 3) & 7)) << 3) + kl] = vv[j];
            }
        }
        // prefetch next tile (overlaps compute below)
        if (kt + 1 < hi) {
            size_t off = (size_t)((kt + 1) * 64 + key) * INNER;
            pk0 = *(const uint4*)(Kbase + off);
            pk1 = *(const uint4*)(Kbase + off + 8);
            pv0 = *(const uint4*)(Vbase + off);
            pv1 = *(const uint4*)(Vbase + off + 8);
        }
        __syncthreads();

        const int j0 = kt * 64;

        // S = Q @ K^T
        floatx4 sacc[4];
#pragma unroll
        for (int cb = 0; cb < 4; ++cb) {
            short8 kf0 = *(const short8*)&Ks[cb * 16 + l15][quad * 8];
            short8 kf1 = *(const short8*)&Ks[cb * 16 + l15][32 + quad * 8];
            floatx4 z = (floatx4){0.f, 0.f, 0.f, 0.f};
            z = __builtin_amdgcn_mfma_f32_16x16x32_bf16(qf0, kf0, z, 0, 0, 0);
            z = __builtin_amdgcn_mfma_f32_16x16x32_bf16(qf1, kf1, z, 0, 0, 0);
            sacc[cb] = z;
        }

        // fixed-max softmax weights
        float p[4][4];
        if (i0 + wave * 16 - (j0 + 63) >= MAXLAG) {
            // fast path: uniform bias, no mask
#pragma unroll
            for (int cb = 0; cb < 4; ++cb)
#pragma unroll
                for (int reg = 0; reg < 4; ++reg)
                    p[cb][reg] = __expf(fmaf(sacc[cb][reg], c1, c2f));
        } else {
#pragma unroll
            for (int cb = 0; cb < 4; ++cb) {
                const int j = j0 + cb * 16 + l15;
#pragma unroll
                for (int reg = 0; reg < 4; ++reg) {
                    const int lag = (ibase + reg) - j;
                    float bias = (lag <= 0) ? lagb[0]
                               : (lag == 1) ? lagb[1]
                               : (lag == 2) ? lagb[2]
                               : (lag == 3) ? lagb[3]
                               : (lag == 4) ? lagb[4] : lagb[5];
                    float e = __expf(fmaf(sacc[cb][reg], c1, bias));
                    p[cb][reg] = (lag < 0) ? 0.f : e;
                }
            }
        }
#pragma unroll
        for (int cb = 0; cb < 4; ++cb)
#pragma unroll
            for (int reg = 0; reg < 4; ++reg)
                lsum[reg] += p[cb][reg];

        // P: C-layout -> LDS -> A-layout (wave-private)
#pragma unroll
        for (int cb = 0; cb < 4; ++cb)
#pragma unroll
            for (int reg = 0; reg < 4; ++reg)
                Pl[wave][quad * 4 + reg][cb * 16 + l15] = f2bf(p[cb][reg]);

        short8 pf0 = *(const short8*)&Pl[wave][l15][quad * 8];
        short8 pf1 = *(const short8*)&Pl[wave][l15][32 + quad * 8];

        // O += P @ V (Vt swizzled reads)
#pragma unroll
        for (int cb = 0; cb < 4; ++cb) {
            const int f = (2 * cb + (l15 >> 3)) & 7;
            short8 vf0 = *(const short8*)&Vt[cb * 16 + l15][(quad ^ f) << 3];
            short8 vf1 = *(const short8*)&Vt[cb * 16 + l15][((4 + quad) ^ f) << 3];
            oacc[cb] = __builtin_amdgcn_mfma_f32_16x16x32_bf16(pf0, vf0, oacc[cb], 0, 0, 0);
            oacc[cb] = __builtin_amdgcn_mfma_f32_16x16x32_bf16(pf1, vf1, oacc[cb], 0, 0, 0);
        }
    }

    // single final l reduction across the 16 lanes of each row group
#pragma unroll
    for (int reg = 0; reg < 4; ++reg) {
        lsum[reg] += __shfl_xor(lsum[reg], 1);
        lsum[reg] += __shfl_xor(lsum[reg], 2);
        lsum[reg] += __shfl_xor(lsum[reg], 4);
        lsum[reg] += __shfl_xor(lsum[reg], 8);
    }

    // store partials (unnormalized O, plus l)
#pragma unroll
    for (int reg = 0; reg < 4; ++reg) {
        const int row = ibase + reg;
        const size_t obase = ((size_t)(sp * 16 + bh) * TT + row) * 64;
#pragma unroll
        for (int cb = 0; cb < 4; ++cb)
            Opart[obase + cb * 16 + l15] = f2bf(oacc[cb][reg]);
        if (l15 == 0)
            Lpart[(size_t)(sp * 16 + bh) * TT + row] = lsum[reg];
    }
}

// ---------------------------------------------------------------------------
// Combine the 2 K-split partials -> ao bf16 [b*T+i][h*64+d]
// ---------------------------------------------------------------------------
#define CMB_UNITS (16 * TT * 16)   // (bh, i, dgroup of 4)

__global__ __launch_bounds__(256)
void combine_kernel(const ushort_t* __restrict__ Opart,
                    const float* __restrict__ Lpart,
                    ushort_t* __restrict__ ao)
{
    int u = blockIdx.x * 256 + threadIdx.x;
    const int bh  = u >> 15;
    const int rem = u & 32767;
    const int i   = rem >> 4;
    const int d   = (rem & 15) * 4;
    const int b   = bh >> 3;
    const int h   = bh & 7;

    const size_t p0 = ((size_t)bh * TT + i) * 64 + d;
    const size_t p1 = ((size_t)(16 + bh) * TT + i) * 64 + d;
    ushort4 a0 = *(const ushort4*)&Opart[p0];
    ushort4 a1 = *(const ushort4*)&Opart[p1];
    const float l = Lpart[(size_t)bh * TT + i] + Lpart[(size_t)(16 + bh) * TT + i];
    const float inv = 1.f / l;

    ushort4 o;
    o.x = f2bf((bf2f(a0.x) + bf2f(a1.x)) * inv);
    o.y = f2bf((bf2f(a0.y) + bf2f(a1.y)) * inv);
    o.z = f2bf((bf2f(a0.z) + bf2f(a1.z)) * inv);
    o.w = f2bf((bf2f(a0.w) + bf2f(a1.w)) * inv);
    *(ushort4*)&ao[((size_t)(b * TT + i)) * INNER + h * DH + d] = o;
}

// ---------------------------------------------------------------------------
extern "C" void kernel_launch(void* const* d_in, const int* in_sizes, int n_in,
                              void* d_out, int out_size, void* d_ws, size_t ws_size,
                              hipStream_t stream)
{
    const float* x  = (const float*)d_in[0];
    const float* Wq = (const float*)d_in[1];
    const float* Wk = (const float*)d_in[2];
    const float* Wv = (const float*)d_in[3];
    const float* Wo = (const float*)d_in[4];
    const float* bo = (const float*)d_in[5];
    const float* lw = (const float*)d_in[6];
    float* out = (float*)d_out;

    const size_t SZ = (size_t)BB * TT * INNER;  // 2M elements
    ushort_t* xb    = (ushort_t*)d_ws;           // 4 MB (reused as ao)
    ushort_t* wqt   = xb + SZ;
    ushort_t* wkt   = wqt + NWE;
    ushort_t* wvt   = wkt + NWE;
    ushort_t* wot   = wvt + NWE;
    ushort_t* q     = wot + NWE;
    ushort_t* k     = q + SZ;
    ushort_t* v     = k + SZ;
    ushort_t* opart = v + SZ;                    // 2 * SZ elements bf16 (8 MB)
    float*    lpart = (float*)(opart + 2 * SZ);  // 2*16*2048 fp32 (0.25 MB)
    ushort_t* ao    = xb;                        // alias: xb dead after QKV gemm

    const int M = BB * TT;  // 4096

    // 1) convert x + weights
    cvt_kernel<<<CVT_UNITS / 256, 256, 0, stream>>>(
        x, Wq, Wk, Wv, Wo, xb, wqt, wkt, wvt, wot);

    // 2) QKV projection
    dim3 gQKV(INNER / TBN, M / TBM, 3);
    gemm_mfma<ushort_t><<<gQKV, 256, 0, stream>>>(
        xb, wqt, wkt, wvt, q, k, v, nullptr, M, INNER, DD);

    // 3) flash attention, K-split x2 -> partials
    dim3 gATT(64, BB * HH);
    attn_mfma<<<gATT, 256, 0, stream>>>(q, k, v, lw, opart, lpart);

    // 4) combine partials -> ao
    combine_kernel<<<CMB_UNITS / 256, 256, 0, stream>>>(opart, lpart, ao);

    // 5) output projection + bias
    dim3 gPRJ(DD / TBN, M / TBM, 1);
    gemm_mfma<float><<<gPRJ, 256, 0, stream>>>(
        ao, wot, wot, wot, out, out, out, bo, M, DD, INNER);
}

// Round 5
// 155.711 us; speedup vs baseline: 5.9035x; 1.0329x over previous
//
#include <hip/hip_runtime.h>
#include <hip/hip_bf16.h>

// Problem constants
#define BB 2
#define TT 2048
#define DD 512
#define HH 8
#define DH 64
#define INNER 512
#define MAXLAG 5

typedef __attribute__((ext_vector_type(8))) short short8;
typedef __attribute__((ext_vector_type(4))) float floatx4;
typedef unsigned short ushort_t;

__device__ inline unsigned short f2bf(float f) {
    unsigned u = __float_as_uint(f);
    unsigned r = (u + 0x7FFFu + ((u >> 16) & 1u)) >> 16;
    return (unsigned short)r;
}
__device__ inline float bf2f(unsigned short u) {
    return __uint_as_float(((unsigned)u) << 16);
}

// async global->LDS, 16B per lane; lds base must be wave-uniform
__device__ inline void gload_lds16(const ushort_t* gp, ushort_t* lp) {
    __builtin_amdgcn_global_load_lds(
        (const __attribute__((address_space(1))) unsigned int*)gp,
        (__attribute__((address_space(3))) unsigned int*)lp, 16, 0, 0);
}

// ---------------------------------------------------------------------------
// x -> bf16 (straight, coalesced)
// ---------------------------------------------------------------------------
#define NXE (BB * TT * DD)
#define UX (NXE / 8)          // 262144 units

__global__ __launch_bounds__(256)
void cvtx_kernel(const float* __restrict__ x, ushort_t* __restrict__ xb)
{
    int u = blockIdx.x * 256 + threadIdx.x;
    int off = u * 8;
    float4 a = *(const float4*)&x[off];
    float4 b = *(const float4*)&x[off + 4];
    ushort_t t[8];
    t[0] = f2bf(a.x); t[1] = f2bf(a.y); t[2] = f2bf(a.z); t[3] = f2bf(a.w);
    t[4] = f2bf(b.x); t[5] = f2bf(b.y); t[6] = f2bf(b.z); t[7] = f2bf(b.w);
    *(uint4*)&xb[off] = *(const uint4*)t;
}

// ---------------------------------------------------------------------------
// Weight transpose+convert via 32x32 LDS tile: Wt[n][k] = bf16(W[k][n]).
// Both global sides coalesced. grid (16,16,4); z picks the weight.
// ---------------------------------------------------------------------------
__global__ __launch_bounds__(256)
void wcvt_kernel(const float* __restrict__ wq, const float* __restrict__ wk,
                 const float* __restrict__ wv, const float* __restrict__ wo,
                 ushort_t* __restrict__ wqt, ushort_t* __restrict__ wkt,
                 ushort_t* __restrict__ wvt, ushort_t* __restrict__ wot)
{
    const float* s = (blockIdx.z == 0) ? wq : (blockIdx.z == 1) ? wk
                   : (blockIdx.z == 2) ? wv : wo;
    ushort_t*    d = (blockIdx.z == 0) ? wqt : (blockIdx.z == 1) ? wkt
                   : (blockIdx.z == 2) ? wvt : wot;
    __shared__ float T[32][33];
    const int k0 = blockIdx.x * 32;
    const int n0 = blockIdx.y * 32;
    {
        const int kk = threadIdx.x >> 3;
        const int n4 = (threadIdx.x & 7) * 4;
        float4 v = *(const float4*)&s[(size_t)(k0 + kk) * 512 + n0 + n4];
        T[kk][n4 + 0] = v.x; T[kk][n4 + 1] = v.y;
        T[kk][n4 + 2] = v.z; T[kk][n4 + 3] = v.w;
    }
    __syncthreads();
    {
        const int nn = threadIdx.x >> 3;
        const int k4 = (threadIdx.x & 7) * 4;
        ushort4 o;
        o.x = f2bf(T[k4 + 0][nn]); o.y = f2bf(T[k4 + 1][nn]);
        o.z = f2bf(T[k4 + 2][nn]); o.w = f2bf(T[k4 + 3][nn]);
        *(ushort4*)&d[(size_t)(n0 + nn) * 512 + k0 + k4] = o;
    }
}

// ---------------------------------------------------------------------------
// bf16 MFMA GEMM, m97-style: global_load_lds staging into FRAGMENT-ORDER LDS.
// LDS granule g (16B) = (m*4 + qchunk); frag reads are lane-linear b128 ->
// conflict-free; staging lane->slot linearity matches global_load_lds HW.
// 128x128x32 tile, 4 waves (2x2), 4x4 16x16x32 MFMAs per wave.
// ---------------------------------------------------------------------------
#define TBM 128
#define TBN 128
#define TBK 32

template <typename OutT>
__global__ __launch_bounds__(256)
void gemm_mfma(const ushort_t* __restrict__ A,
               const ushort_t* __restrict__ B0, const ushort_t* __restrict__ B1,
               const ushort_t* __restrict__ B2,
               OutT* __restrict__ O0, OutT* __restrict__ O1, OutT* __restrict__ O2,
               const float* __restrict__ bias, int M, int N, int K)
{
    const ushort_t* Bw = (blockIdx.z == 0) ? B0 : ((blockIdx.z == 1) ? B1 : B2);
    OutT*           O  = (blockIdx.z == 0) ? O0 : ((blockIdx.z == 1) ? O1 : O2);

    __shared__ ushort_t As[TBM * TBK];   // granule g = m*4+q -> A[m][q*8..+8]
    __shared__ ushort_t Bs[TBN * TBK];

    const int tid  = threadIdx.x;
    const int wave = tid >> 6;
    const int lane = tid & 63;
    const int quad = lane >> 4;
    const int l15  = lane & 15;
    const int wr   = wave >> 1;
    const int wc   = wave & 1;
    const int bm   = blockIdx.y * TBM;
    const int bn   = blockIdx.x * TBN;

    // staging: wave w covers granules [w*128, w*128+128), two issues of 64
    const int g0 = wave * 128 + lane;
    const int g1 = g0 + 64;
    const int m0 = g0 >> 2, q0 = g0 & 3;
    const int m1 = g1 >> 2, q1 = g1 & 3;
    const ushort_t* a0p = &A[(size_t)(bm + m0) * K + q0 * 8];
    const ushort_t* a1p = &A[(size_t)(bm + m1) * K + q1 * 8];
    const ushort_t* b0p = &Bw[(size_t)(bn + m0) * K + q0 * 8];
    const ushort_t* b1p = &Bw[(size_t)(bn + m1) * K + q1 * 8];
    ushort_t* lA0 = &As[(wave * 128) * 8];       // wave-uniform bases
    ushort_t* lA1 = &As[(wave * 128 + 64) * 8];
    ushort_t* lB0 = &Bs[(wave * 128) * 8];
    ushort_t* lB1 = &Bs[(wave * 128 + 64) * 8];

    floatx4 acc[4][4];
#pragma unroll
    for (int i = 0; i < 4; ++i)
#pragma unroll
        for (int j = 0; j < 4; ++j) acc[i][j] = (floatx4){0.f, 0.f, 0.f, 0.f};

    for (int k0 = 0; k0 < K; k0 += TBK) {
        __syncthreads();
        gload_lds16(a0p + k0, lA0);
        gload_lds16(a1p + k0, lA1);
        gload_lds16(b0p + k0, lB0);
        gload_lds16(b1p + k0, lB1);
        __syncthreads();

        short8 af[4], bf[4];
#pragma unroll
        for (int mt = 0; mt < 4; ++mt)
            af[mt] = *(const short8*)&As[(((wr * 64 + mt * 16 + l15) << 2) + quad) * 8];
#pragma unroll
        for (int nt = 0; nt < 4; ++nt)
            bf[nt] = *(const short8*)&Bs[(((wc * 64 + nt * 16 + l15) << 2) + quad) * 8];
#pragma unroll
        for (int mt = 0; mt < 4; ++mt)
#pragma unroll
            for (int nt = 0; nt < 4; ++nt)
                acc[mt][nt] = __builtin_amdgcn_mfma_f32_16x16x32_bf16(
                    af[mt], bf[nt], acc[mt][nt], 0, 0, 0);
    }

    float bv[4] = {0.f, 0.f, 0.f, 0.f};
    if (bias) {
#pragma unroll
        for (int nt = 0; nt < 4; ++nt)
            bv[nt] = bias[bn + wc * 64 + nt * 16 + l15];
    }
#pragma unroll
    for (int mt = 0; mt < 4; ++mt) {
#pragma unroll
        for (int nt = 0; nt < 4; ++nt) {
            const int n = bn + wc * 64 + nt * 16 + l15;
#pragma unroll
            for (int reg = 0; reg < 4; ++reg) {
                const int m = bm + wr * 64 + mt * 16 + quad * 4 + reg;
                float v = acc[mt][nt][reg] + bv[nt];
                if constexpr (sizeof(OutT) == 2)
                    O[(size_t)m * N + n] = (OutT)f2bf(v);
                else
                    O[(size_t)m * N + n] = (OutT)v;
            }
        }
    }
}

// ---------------------------------------------------------------------------
// MFMA flash attention: UNIFORM 8-tile chunks. grid (32, 4, 16):
// qt = 31-bx, slot = by covers kt in [slot*8, min(slot*8+8, qt+1)),
// bh = bz. Blocks with slot*8 > qt exit. Fixed-max softmax (MFIX), register
// prefetch, XOR-swizzled Vt. Partials: Opart[slot][bh][i][d], Lpart fp32.
// ---------------------------------------------------------------------------
#define PAD 72
#define MFIX 10.0f
#define CS 8          // kt tiles per chunk
#define NSLOT 4

__global__ __launch_bounds__(256)
void attn_mfma(const ushort_t* __restrict__ Qg,
               const ushort_t* __restrict__ Kg,
               const ushort_t* __restrict__ Vg,
               const float* __restrict__ lagw,
               ushort_t* __restrict__ Opart,
               float* __restrict__ Lpart)
{
    const int qt   = 31 - blockIdx.x;
    const int slot = blockIdx.y;
    const int lo   = slot * CS;
    if (lo > qt) return;
    const int hi = min(qt + 1, lo + CS);

    __shared__ ushort_t Ks[64][PAD];
    __shared__ ushort_t Vt[64][PAD];
    __shared__ ushort_t Pl[4][16][PAD];

    const int tid  = threadIdx.x;
    const int wave = tid >> 6;
    const int lane = tid & 63;
    const int quad = lane >> 4;
    const int l15  = lane & 15;

    const int bh = blockIdx.z;
    const int b  = bh >> 3;
    const int h  = bh & 7;
    const int i0 = qt * 64;

    float lagb[MAXLAG + 1];
    {
        float mx = -1e30f;
#pragma unroll
        for (int l = 0; l <= MAXLAG; ++l) {
            lagb[l] = lagw[h * (MAXLAG + 1) + l];
            mx = fmaxf(mx, lagb[l]);
        }
        float s = 0.f;
#pragma unroll
        for (int l = 0; l <= MAXLAG; ++l) { lagb[l] = __expf(lagb[l] - mx); s += lagb[l]; }
        float inv = 1.f / s;
#pragma unroll
        for (int l = 0; l <= MAXLAG; ++l) lagb[l] = lagb[l] * inv - MFIX;
    }
    const float c1  = 0.125f;
    const float c2f = lagb[MAXLAG];

    short8 qf0, qf1;
    {
        const ushort_t* qbase =
            Qg + ((size_t)(b * TT + i0 + wave * 16 + l15)) * INNER + h * DH;
        qf0 = *(const short8*)(qbase + quad * 8);
        qf1 = *(const short8*)(qbase + 32 + quad * 8);
    }

    floatx4 oacc[4];
    float lsum[4] = {0.f, 0.f, 0.f, 0.f};
#pragma unroll
    for (int cb = 0; cb < 4; ++cb) oacc[cb] = (floatx4){0.f, 0.f, 0.f, 0.f};

    const int ibase = i0 + wave * 16 + quad * 4;
    const int key = tid >> 2;
    const int dg  = (tid & 3) * 16;
    const ushort_t* Kbase = Kg + ((size_t)b * TT) * INNER + h * DH + dg;
    const ushort_t* Vbase = Vg + ((size_t)b * TT) * INNER + h * DH + dg;

    uint4 pk0, pk1, pv0, pv1;
    {
        size_t off = (size_t)(lo * 64 + key) * INNER;
        pk0 = *(const uint4*)(Kbase + off);
        pk1 = *(const uint4*)(Kbase + off + 8);
        pv0 = *(const uint4*)(Vbase + off);
        pv1 = *(const uint4*)(Vbase + off + 8);
    }

    for (int kt = lo; kt < hi; ++kt) {
        __syncthreads();
        *(uint4*)&Ks[key][dg]     = pk0;
        *(uint4*)&Ks[key][dg + 8] = pk1;
        {
            ushort_t vv[16];
            *(uint4*)&vv[0] = pv0;
            *(uint4*)&vv[8] = pv1;
            const int kc = key >> 3, kl = key & 7;
#pragma unroll
            for (int j = 0; j < 16; ++j) {
                const int d = dg + j;
                Vt[d][((kc ^ ((d >> 3) & 7)) << 3) + kl] = vv[j];
            }
        }
        if (kt + 1 < hi) {
            size_t off = (size_t)((kt + 1) * 64 + key) * INNER;
            pk0 = *(const uint4*)(Kbase + off);
            pk1 = *(const uint4*)(Kbase + off + 8);
            pv0 = *(const uint4*)(Vbase + off);
            pv1 = *(const uint4*)(Vbase + off + 8);
        }
        __syncthreads();

        const int j0 = kt * 64;

        floatx4 sacc[4];
#pragma unroll
        for (int cb = 0; cb < 4; ++cb) {
            short8 kf0 = *(const short8*)&Ks[cb * 16 + l15][quad * 8];
            short8 kf1 = *(const short8*)&Ks[cb * 16 + l15][32 + quad * 8];
            floatx4 z = (floatx4){0.f, 0.f, 0.f, 0.f};
            z = __builtin_amdgcn_mfma_f32_16x16x32_bf16(qf0, kf0, z, 0, 0, 0);
            z = __builtin_amdgcn_mfma_f32_16x16x32_bf16(qf1, kf1, z, 0, 0, 0);
            sacc[cb] = z;
        }

        float p[4][4];
        if (i0 + wave * 16 - (j0 + 63) >= MAXLAG) {
#pragma unroll
            for (int cb = 0; cb < 4; ++cb)
#pragma unroll
                for (int reg = 0; reg < 4; ++reg)
                    p[cb][reg] = __expf(fmaf(sacc[cb][reg], c1, c2f));
        } else {
#pragma unroll
            for (int cb = 0; cb < 4; ++cb) {
                const int j = j0 + cb * 16 + l15;
#pragma unroll
                for (int reg = 0; reg < 4; ++reg) {
                    const int lag = (ibase + reg) - j;
                    float bias = (lag <= 0) ? lagb[0]
                               : (lag == 1) ? lagb[1]
                               : (lag == 2) ? lagb[2]
                               : (lag == 3) ? lagb[3]
                               : (lag == 4) ? lagb[4] : lagb[5];
                    float e = __expf(fmaf(sacc[cb][reg], c1, bias));
                    p[cb][reg] = (lag < 0) ? 0.f : e;
                }
            }
        }
#pragma unroll
        for (int cb = 0; cb < 4; ++cb)
#pragma unroll
            for (int reg = 0; reg < 4; ++reg)
                lsum[reg] += p[cb][reg];

#pragma unroll
        for (int cb = 0; cb < 4; ++cb)
#pragma unroll
            for (int reg = 0; reg < 4; ++reg)
                Pl[wave][quad * 4 + reg][cb * 16 + l15] = f2bf(p[cb][reg]);

        short8 pf0 = *(const short8*)&Pl[wave][l15][quad * 8];
        short8 pf1 = *(const short8*)&Pl[wave][l15][32 + quad * 8];

#pragma unroll
        for (int cb = 0; cb < 4; ++cb) {
            const int f = (2 * cb + (l15 >> 3)) & 7;
            short8 vf0 = *(const short8*)&Vt[cb * 16 + l15][(quad ^ f) << 3];
            short8 vf1 = *(const short8*)&Vt[cb * 16 + l15][((4 + quad) ^ f) << 3];
            oacc[cb] = __builtin_amdgcn_mfma_f32_16x16x32_bf16(pf0, vf0, oacc[cb], 0, 0, 0);
            oacc[cb] = __builtin_amdgcn_mfma_f32_16x16x32_bf16(pf1, vf1, oacc[cb], 0, 0, 0);
        }
    }

#pragma unroll
    for (int reg = 0; reg < 4; ++reg) {
        lsum[reg] += __shfl_xor(lsum[reg], 1);
        lsum[reg] += __shfl_xor(lsum[reg], 2);
        lsum[reg] += __shfl_xor(lsum[reg], 4);
        lsum[reg] += __shfl_xor(lsum[reg], 8);
    }

#pragma unroll
    for (int reg = 0; reg < 4; ++reg) {
        const int row = ibase + reg;
        const size_t obase = ((size_t)(slot * 16 + bh) * TT + row) * 64;
#pragma unroll
        for (int cb = 0; cb < 4; ++cb)
            Opart[obase + cb * 16 + l15] = f2bf(oacc[cb][reg]);
        if (l15 == 0)
            Lpart[(size_t)(slot * 16 + bh) * TT + row] = lsum[reg];
    }
}

// ---------------------------------------------------------------------------
// Combine up to 4 K-split partials -> ao bf16 [b*T+i][h*64+d]
// ---------------------------------------------------------------------------
#define CMB_UNITS (16 * TT * 16)

__global__ __launch_bounds__(256)
void combine_kernel(const ushort_t* __restrict__ Opart,
                    const float* __restrict__ Lpart,
                    ushort_t* __restrict__ ao)
{
    int u = blockIdx.x * 256 + threadIdx.x;
    const int bh  = u >> 15;
    const int rem = u & 32767;
    const int i   = rem >> 4;
    const int d   = (rem & 15) * 4;
    const int b   = bh >> 3;
    const int h   = bh & 7;
    const int qt  = i >> 6;
    const int nch = (qt + CS) >> 3;   // ceil((qt+1)/8)

    float sx = 0.f, sy = 0.f, sz = 0.f, sw = 0.f, l = 0.f;
    for (int s = 0; s < nch; ++s) {
        const size_t p = ((size_t)(s * 16 + bh) * TT + i) * 64 + d;
        ushort4 a = *(const ushort4*)&Opart[p];
        sx += bf2f(a.x); sy += bf2f(a.y); sz += bf2f(a.z); sw += bf2f(a.w);
        l += Lpart[(size_t)(s * 16 + bh) * TT + i];
    }
    const float inv = 1.f / l;
    ushort4 o;
    o.x = f2bf(sx * inv); o.y = f2bf(sy * inv);
    o.z = f2bf(sz * inv); o.w = f2bf(sw * inv);
    *(ushort4*)&ao[((size_t)(b * TT + i)) * INNER + h * DH + d] = o;
}

// ---------------------------------------------------------------------------
extern "C" void kernel_launch(void* const* d_in, const int* in_sizes, int n_in,
                              void* d_out, int out_size, void* d_ws, size_t ws_size,
                              hipStream_t stream)
{
    const float* x  = (const float*)d_in[0];
    const float* Wq = (const float*)d_in[1];
    const float* Wk = (const float*)d_in[2];
    const float* Wv = (const float*)d_in[3];
    const float* Wo = (const float*)d_in[4];
    const float* bo = (const float*)d_in[5];
    const float* lw = (const float*)d_in[6];
    float* out = (float*)d_out;

    const size_t SZ  = (size_t)BB * TT * INNER;  // 2M elements
    const size_t NWE = (size_t)DD * INNER;       // 256K per weight
    ushort_t* xb    = (ushort_t*)d_ws;
    ushort_t* wqt   = xb + SZ;
    ushort_t* wkt   = wqt + NWE;
    ushort_t* wvt   = wkt + NWE;
    ushort_t* wot   = wvt + NWE;
    ushort_t* q     = wot + NWE;
    ushort_t* k     = q + SZ;
    ushort_t* v     = k + SZ;
    ushort_t* opart = v + SZ;                    // NSLOT * 16*TT*64 = 8M elems
    float*    lpart = (float*)(opart + (size_t)NSLOT * 16 * TT * 64);
    ushort_t* ao    = xb;                        // alias: xb dead after QKV

    const int M = BB * TT;

    cvtx_kernel<<<UX / 256, 256, 0, stream>>>(x, xb);
    wcvt_kernel<<<dim3(16, 16, 4), 256, 0, stream>>>(
        Wq, Wk, Wv, Wo, wqt, wkt, wvt, wot);

    dim3 gQKV(INNER / TBN, M / TBM, 3);
    gemm_mfma<ushort_t><<<gQKV, 256, 0, stream>>>(
        xb, wqt, wkt, wvt, q, k, v, nullptr, M, INNER, DD);

    dim3 gATT(32, NSLOT, BB * HH);
    attn_mfma<<<gATT, 256, 0, stream>>>(q, k, v, lw, opart, lpart);

    combine_kernel<<<CMB_UNITS / 256, 256, 0, stream>>>(opart, lpart, ao);

    dim3 gPRJ(DD / TBN, M / TBM, 1);
    gemm_mfma<float><<<gPRJ, 256, 0, stream>>>(
        ao, wot, wot, wot, out, out, out, bo, M, DD, INNER);
}

// Round 7
// 138.609 us; speedup vs baseline: 6.6318x; 1.1234x over previous
//
#include <hip/hip_runtime.h>
#include <hip/hip_bf16.h>

// Problem constants
#define BB 2
#define TT 2048
#define DD 512
#define HH 8
#define DH 64
#define INNER 512
#define MAXLAG 5

typedef __attribute__((ext_vector_type(8))) short short8;
typedef __attribute__((ext_vector_type(4))) float floatx4;
typedef unsigned short ushort_t;

__device__ inline unsigned short f2bf(float f) {
    unsigned u = __float_as_uint(f);
    unsigned r = (u + 0x7FFFu + ((u >> 16) & 1u)) >> 16;
    return (unsigned short)r;
}
__device__ inline float bf2f(unsigned short u) {
    return __uint_as_float(((unsigned)u) << 16);
}

// ---------------------------------------------------------------------------
// Fused convert: blocks [0,1024): x -> bf16; blocks [1024,2048): weight
// transpose+convert via 32x32 LDS tile (Wt[n][k] = bf16(W[k][n])).
// ---------------------------------------------------------------------------
#define NXE (BB * TT * DD)

__global__ __launch_bounds__(256)
void cvt_kernel(const float* __restrict__ x,
                const float* __restrict__ wq, const float* __restrict__ wk,
                const float* __restrict__ wv, const float* __restrict__ wo,
                ushort_t* __restrict__ xb,
                ushort_t* __restrict__ wqt, ushort_t* __restrict__ wkt,
                ushort_t* __restrict__ wvt, ushort_t* __restrict__ wot)
{
    __shared__ float T[32][33];
    const int bid = blockIdx.x;
    if (bid < 1024) {
        int off = (bid * 256 + threadIdx.x) * 8;
        float4 a = *(const float4*)&x[off];
        float4 b = *(const float4*)&x[off + 4];
        ushort_t t[8];
        t[0] = f2bf(a.x); t[1] = f2bf(a.y); t[2] = f2bf(a.z); t[3] = f2bf(a.w);
        t[4] = f2bf(b.x); t[5] = f2bf(b.y); t[6] = f2bf(b.z); t[7] = f2bf(b.w);
        *(uint4*)&xb[off] = *(const uint4*)t;
        return;
    }
    const int r = bid - 1024;
    const int z = r >> 8;
    const int tile = r & 255;
    const float* s = (z == 0) ? wq : (z == 1) ? wk : (z == 2) ? wv : wo;
    ushort_t*    d = (z == 0) ? wqt : (z == 1) ? wkt : (z == 2) ? wvt : wot;
    const int k0 = (tile & 15) * 32;
    const int n0 = (tile >> 4) * 32;
    {
        const int kk = threadIdx.x >> 3;
        const int n4 = (threadIdx.x & 7) * 4;
        float4 v = *(const float4*)&s[(size_t)(k0 + kk) * 512 + n0 + n4];
        T[kk][n4 + 0] = v.x; T[kk][n4 + 1] = v.y;
        T[kk][n4 + 2] = v.z; T[kk][n4 + 3] = v.w;
    }
    __syncthreads();
    {
        const int nn = threadIdx.x >> 3;
        const int k4 = (threadIdx.x & 7) * 4;
        ushort4 o;
        o.x = f2bf(T[k4 + 0][nn]); o.y = f2bf(T[k4 + 1][nn]);
        o.z = f2bf(T[k4 + 2][nn]); o.w = f2bf(T[k4 + 3][nn]);
        *(ushort4*)&d[(size_t)(n0 + nn) * 512 + k0 + k4] = o;
    }
}

// ---------------------------------------------------------------------------
// bf16 MFMA GEMM, 64x64x32 tiles for occupancy (QKV: 1536 blocks = 6/CU).
// Register-prefetch pipeline; LDS in fragment-granule order (granule = tid,
// 16B), frag reads are full-window b128 -> conflict-free.
// vtrans: for blockIdx.z==2 the epilogue writes V TRANSPOSED per (b,h):
// O2[((b*8+h)*64 + d) * 2048 + t] -- a packed ushort4 store (reg -> t).
// ---------------------------------------------------------------------------
#define GM 64
#define GN 64
#define GK 32

template <typename OutT>
__global__ __launch_bounds__(256)
void gemm64(const ushort_t* __restrict__ A,
            const ushort_t* __restrict__ B0, const ushort_t* __restrict__ B1,
            const ushort_t* __restrict__ B2,
            OutT* __restrict__ O0, OutT* __restrict__ O1, OutT* __restrict__ O2,
            const float* __restrict__ bias, int M, int N, int K, int vtrans)
{
    const ushort_t* Bw = (blockIdx.z == 0) ? B0 : ((blockIdx.z == 1) ? B1 : B2);
    OutT*           O  = (blockIdx.z == 0) ? O0 : ((blockIdx.z == 1) ? O1 : O2);
    const int dotrans = vtrans && (blockIdx.z == 2);

    __shared__ ushort_t As[GM * GK];   // granule g = m*4+c -> A[m][c*8..+8]
    __shared__ ushort_t Bs[GN * GK];

    const int tid  = threadIdx.x;
    const int wave = tid >> 6;
    const int lane = tid & 63;
    const int quad = lane >> 4;
    const int l15  = lane & 15;
    const int wr   = wave >> 1;
    const int wc   = wave & 1;
    const int bm   = blockIdx.y * GM;
    const int bn   = blockIdx.x * GN;

    // staging: thread t owns granule t: m = t>>2, c = t&3 (coalesced loads)
    const ushort_t* ap = &A[(size_t)(bm + (tid >> 2)) * K + (tid & 3) * 8];
    const ushort_t* bp = &Bw[(size_t)(bn + (tid >> 2)) * K + (tid & 3) * 8];

    floatx4 acc[2][2];
#pragma unroll
    for (int i = 0; i < 2; ++i)
#pragma unroll
        for (int j = 0; j < 2; ++j) acc[i][j] = (floatx4){0.f, 0.f, 0.f, 0.f};

    uint4 pa = *(const uint4*)ap;
    uint4 pb = *(const uint4*)bp;

    for (int k0 = 0; k0 < K; k0 += GK) {
        __syncthreads();
        *(uint4*)&As[tid * 8] = pa;
        *(uint4*)&Bs[tid * 8] = pb;
        if (k0 + GK < K) {
            pa = *(const uint4*)(ap + k0 + GK);
            pb = *(const uint4*)(bp + k0 + GK);
        }
        __syncthreads();

        short8 af[2], bf[2];
#pragma unroll
        for (int mt = 0; mt < 2; ++mt)
            af[mt] = *(const short8*)&As[(((wr * 32 + mt * 16 + l15) << 2) + quad) * 8];
#pragma unroll
        for (int nt = 0; nt < 2; ++nt)
            bf[nt] = *(const short8*)&Bs[(((wc * 32 + nt * 16 + l15) << 2) + quad) * 8];
#pragma unroll
        for (int mt = 0; mt < 2; ++mt)
#pragma unroll
            for (int nt = 0; nt < 2; ++nt)
                acc[mt][nt] = __builtin_amdgcn_mfma_f32_16x16x32_bf16(
                    af[mt], bf[nt], acc[mt][nt], 0, 0, 0);
    }

    if (dotrans) {
        // V^T store: col n -> (h,d); 4 regs -> 4 consecutive t -> ushort4
#pragma unroll
        for (int mt = 0; mt < 2; ++mt) {
            const int m0 = bm + wr * 32 + mt * 16 + quad * 4;
            const int b  = m0 >> 11;
            const int t0 = m0 & 2047;
#pragma unroll
            for (int nt = 0; nt < 2; ++nt) {
                const int n = bn + wc * 32 + nt * 16 + l15;
                const int h = n >> 6, dd = n & 63;
                ushort4 o;
                o.x = f2bf(acc[mt][nt][0]); o.y = f2bf(acc[mt][nt][1]);
                o.z = f2bf(acc[mt][nt][2]); o.w = f2bf(acc[mt][nt][3]);
                *(ushort4*)&((ushort_t*)O)[((size_t)((b * 8 + h) * 64 + dd)) * 2048 + t0] = o;
            }
        }
        return;
    }

    float bv[2] = {0.f, 0.f};
    if (bias) {
#pragma unroll
        for (int nt = 0; nt < 2; ++nt)
            bv[nt] = bias[bn + wc * 32 + nt * 16 + l15];
    }
#pragma unroll
    for (int mt = 0; mt < 2; ++mt) {
#pragma unroll
        for (int nt = 0; nt < 2; ++nt) {
            const int n = bn + wc * 32 + nt * 16 + l15;
#pragma unroll
            for (int reg = 0; reg < 4; ++reg) {
                const int m = bm + wr * 32 + mt * 16 + quad * 4 + reg;
                float v = acc[mt][nt][reg] + bv[nt];
                if constexpr (sizeof(OutT) == 2)
                    O[(size_t)m * N + n] = (OutT)f2bf(v);
                else
                    O[(size_t)m * N + n] = (OutT)v;
            }
        }
    }
}

// ---------------------------------------------------------------------------
// MFMA flash attention v3 (FIXED): K natural [t][inner], V pre-transposed
// [bh][d][t]. Each thread stages TWO 16B granules per tile (rows srow and
// srow+32) so the full 64-row tile is covered (R6 bug: only half staged).
// Chunk-swizzled granules: granule(row,c) = row*8 + ((c+row)&7).
// 2-way K-split, fixed-max softmax.
// ---------------------------------------------------------------------------
#define PAD 72
#define MFIX 10.0f

__global__ __launch_bounds__(256)
void attn_mfma(const ushort_t* __restrict__ Qg,
               const ushort_t* __restrict__ Kg,
               const ushort_t* __restrict__ Vtg,
               const float* __restrict__ lagw,
               ushort_t* __restrict__ Opart,
               float* __restrict__ Lpart)
{
    __shared__ ushort_t Ks[64 * 8 * 8];    // 512 granules of 8 ushorts
    __shared__ ushort_t Vts[64 * 8 * 8];
    __shared__ ushort_t Pl[4][16][PAD];

    const int tid  = threadIdx.x;
    const int wave = tid >> 6;
    const int lane = tid & 63;
    const int quad = lane >> 4;
    const int l15  = lane & 15;

    const int bh = blockIdx.y;
    const int b  = bh >> 3;
    const int h  = bh & 7;
    const int c  = blockIdx.x;         // heavy qt first
    const int qt = 31 - (c >> 1);
    const int sp = c & 1;
    const int i0 = qt * 64;
    const int h1 = (qt + 1) >> 1;
    const int lo = sp ? h1 : 0;
    const int hi = sp ? (qt + 1) : h1;

    float lagb[MAXLAG + 1];
    {
        float mx = -1e30f;
#pragma unroll
        for (int l = 0; l <= MAXLAG; ++l) {
            lagb[l] = lagw[h * (MAXLAG + 1) + l];
            mx = fmaxf(mx, lagb[l]);
        }
        float s = 0.f;
#pragma unroll
        for (int l = 0; l <= MAXLAG; ++l) { lagb[l] = __expf(lagb[l] - mx); s += lagb[l]; }
        float inv = 1.f / s;
#pragma unroll
        for (int l = 0; l <= MAXLAG; ++l) lagb[l] = lagb[l] * inv - MFIX;
    }
    const float c1  = 0.125f;
    const float c2f = lagb[MAXLAG];

    short8 qf0, qf1;
    {
        const ushort_t* qbase =
            Qg + ((size_t)(b * TT + i0 + wave * 16 + l15)) * INNER + h * DH;
        qf0 = *(const short8*)(qbase + quad * 8);
        qf1 = *(const short8*)(qbase + 32 + quad * 8);
    }

    floatx4 oacc[4];
    float lsum[4] = {0.f, 0.f, 0.f, 0.f};
#pragma unroll
    for (int cb = 0; cb < 4; ++cb) oacc[cb] = (floatx4){0.f, 0.f, 0.f, 0.f};

    const int ibase = i0 + wave * 16 + quad * 4;

    // staging: thread t owns rows srow and srow+32, chunk sc (16B each);
    // coalesced: 8 threads cover one row's 64 elements.
    const int srow = tid >> 3;          // 0..31
    const int sc   = tid & 7;
    const ushort_t* Kp0 = Kg + ((size_t)(b * TT) + srow) * INNER + h * DH + sc * 8;
    const ushort_t* Kp1 = Kp0 + (size_t)32 * INNER;
    const ushort_t* Vp0 = Vtg + ((size_t)(bh * 64 + srow)) * 2048 + sc * 8;
    const ushort_t* Vp1 = Vp0 + (size_t)32 * 2048;
    const int slot = (sc + srow) & 7;   // same for srow+32 (32 % 8 == 0)
    const int kdst0 = ((srow << 3) + slot) << 3;
    const int kdst1 = (((srow + 32) << 3) + slot) << 3;

    uint4 pk0, pk1, pv0, pv1;
    if (lo < hi) {
        const size_t koff = (size_t)(lo * 64) * INNER;
        pk0 = *(const uint4*)(Kp0 + koff);
        pk1 = *(const uint4*)(Kp1 + koff);
        pv0 = *(const uint4*)(Vp0 + lo * 64);
        pv1 = *(const uint4*)(Vp1 + lo * 64);
    }

    for (int kt = lo; kt < hi; ++kt) {
        __syncthreads();
        *(uint4*)&Ks[kdst0]  = pk0;
        *(uint4*)&Ks[kdst1]  = pk1;
        *(uint4*)&Vts[kdst0] = pv0;
        *(uint4*)&Vts[kdst1] = pv1;
        if (kt + 1 < hi) {
            const size_t koff = (size_t)((kt + 1) * 64) * INNER;
            pk0 = *(const uint4*)(Kp0 + koff);
            pk1 = *(const uint4*)(Kp1 + koff);
            pv0 = *(const uint4*)(Vp0 + (kt + 1) * 64);
            pv1 = *(const uint4*)(Vp1 + (kt + 1) * 64);
        }
        __syncthreads();

        const int j0 = kt * 64;

        floatx4 sacc[4];
#pragma unroll
        for (int cb = 0; cb < 4; ++cb) {
            const int key = cb * 16 + l15;
            short8 kf0 = *(const short8*)&Ks[((key << 3) + ((quad + key) & 7)) << 3];
            short8 kf1 = *(const short8*)&Ks[((key << 3) + ((quad + 4 + key) & 7)) << 3];
            floatx4 z = (floatx4){0.f, 0.f, 0.f, 0.f};
            z = __builtin_amdgcn_mfma_f32_16x16x32_bf16(qf0, kf0, z, 0, 0, 0);
            z = __builtin_amdgcn_mfma_f32_16x16x32_bf16(qf1, kf1, z, 0, 0, 0);
            sacc[cb] = z;
        }

        float p[4][4];
        if (i0 + wave * 16 - (j0 + 63) >= MAXLAG) {
#pragma unroll
            for (int cb = 0; cb < 4; ++cb)
#pragma unroll
                for (int reg = 0; reg < 4; ++reg)
                    p[cb][reg] = __expf(fmaf(sacc[cb][reg], c1, c2f));
        } else {
#pragma unroll
            for (int cb = 0; cb < 4; ++cb) {
                const int j = j0 + cb * 16 + l15;
#pragma unroll
                for (int reg = 0; reg < 4; ++reg) {
                    const int lag = (ibase + reg) - j;
                    float bias = (lag <= 0) ? lagb[0]
                               : (lag == 1) ? lagb[1]
                               : (lag == 2) ? lagb[2]
                               : (lag == 3) ? lagb[3]
                               : (lag == 4) ? lagb[4] : lagb[5];
                    float e = __expf(fmaf(sacc[cb][reg], c1, bias));
                    p[cb][reg] = (lag < 0) ? 0.f : e;
                }
            }
        }
#pragma unroll
        for (int cb = 0; cb < 4; ++cb)
#pragma unroll
            for (int reg = 0; reg < 4; ++reg)
                lsum[reg] += p[cb][reg];

#pragma unroll
        for (int cb = 0; cb < 4; ++cb)
#pragma unroll
            for (int reg = 0; reg < 4; ++reg)
                Pl[wave][quad * 4 + reg][cb * 16 + l15] = f2bf(p[cb][reg]);

        short8 pf0 = *(const short8*)&Pl[wave][l15][quad * 8];
        short8 pf1 = *(const short8*)&Pl[wave][l15][32 + quad * 8];

#pragma unroll
        for (int cb = 0; cb < 4; ++cb) {
            const int dd = cb * 16 + l15;
            short8 vf0 = *(const short8*)&Vts[((dd << 3) + ((quad + dd) & 7)) << 3];
            short8 vf1 = *(const short8*)&Vts[((dd << 3) + ((quad + 4 + dd) & 7)) << 3];
            oacc[cb] = __builtin_amdgcn_mfma_f32_16x16x32_bf16(pf0, vf0, oacc[cb], 0, 0, 0);
            oacc[cb] = __builtin_amdgcn_mfma_f32_16x16x32_bf16(pf1, vf1, oacc[cb], 0, 0, 0);
        }
    }

#pragma unroll
    for (int reg = 0; reg < 4; ++reg) {
        lsum[reg] += __shfl_xor(lsum[reg], 1);
        lsum[reg] += __shfl_xor(lsum[reg], 2);
        lsum[reg] += __shfl_xor(lsum[reg], 4);
        lsum[reg] += __shfl_xor(lsum[reg], 8);
    }

#pragma unroll
    for (int reg = 0; reg < 4; ++reg) {
        const int row = ibase + reg;
        const size_t obase = ((size_t)(sp * 16 + bh) * TT + row) * 64;
#pragma unroll
        for (int cb = 0; cb < 4; ++cb)
            Opart[obase + cb * 16 + l15] = f2bf(oacc[cb][reg]);
        if (l15 == 0)
            Lpart[(size_t)(sp * 16 + bh) * TT + row] = lsum[reg];
    }
}

// ---------------------------------------------------------------------------
// Combine the 2 K-split partials -> ao bf16 [b*T+i][h*64+d]
// ---------------------------------------------------------------------------
#define CMB_UNITS (16 * TT * 16)

__global__ __launch_bounds__(256)
void combine_kernel(const ushort_t* __restrict__ Opart,
                    const float* __restrict__ Lpart,
                    ushort_t* __restrict__ ao)
{
    int u = blockIdx.x * 256 + threadIdx.x;
    const int bh  = u >> 15;
    const int rem = u & 32767;
    const int i   = rem >> 4;
    const int d   = (rem & 15) * 4;
    const int b   = bh >> 3;
    const int h   = bh & 7;

    const size_t p0 = ((size_t)bh * TT + i) * 64 + d;
    const size_t p1 = ((size_t)(16 + bh) * TT + i) * 64 + d;
    ushort4 a0 = *(const ushort4*)&Opart[p0];
    ushort4 a1 = *(const ushort4*)&Opart[p1];
    const float l = Lpart[(size_t)bh * TT + i] + Lpart[(size_t)(16 + bh) * TT + i];
    const float inv = 1.f / l;

    ushort4 o;
    o.x = f2bf((bf2f(a0.x) + bf2f(a1.x)) * inv);
    o.y = f2bf((bf2f(a0.y) + bf2f(a1.y)) * inv);
    o.z = f2bf((bf2f(a0.z) + bf2f(a1.z)) * inv);
    o.w = f2bf((bf2f(a0.w) + bf2f(a1.w)) * inv);
    *(ushort4*)&ao[((size_t)(b * TT + i)) * INNER + h * DH + d] = o;
}

// ---------------------------------------------------------------------------
extern "C" void kernel_launch(void* const* d_in, const int* in_sizes, int n_in,
                              void* d_out, int out_size, void* d_ws, size_t ws_size,
                              hipStream_t stream)
{
    const float* x  = (const float*)d_in[0];
    const float* Wq = (const float*)d_in[1];
    const float* Wk = (const float*)d_in[2];
    const float* Wv = (const float*)d_in[3];
    const float* Wo = (const float*)d_in[4];
    const float* bo = (const float*)d_in[5];
    const float* lw = (const float*)d_in[6];
    float* out = (float*)d_out;

    const size_t SZ  = (size_t)BB * TT * INNER;  // 2M elements
    const size_t NWE = (size_t)DD * INNER;       // 256K per weight
    ushort_t* xb    = (ushort_t*)d_ws;
    ushort_t* wqt   = xb + SZ;
    ushort_t* wkt   = wqt + NWE;
    ushort_t* wvt   = wkt + NWE;
    ushort_t* wot   = wvt + NWE;
    ushort_t* q     = wot + NWE;
    ushort_t* k     = q + SZ;
    ushort_t* vt    = k + SZ;                    // V TRANSPOSED [bh][d][t]
    ushort_t* opart = vt + SZ;                   // 2 slots * 16*TT*64
    float*    lpart = (float*)(opart + 2 * SZ);
    ushort_t* ao    = xb;                        // alias: xb dead after QKV

    const int M = BB * TT;

    cvt_kernel<<<2048, 256, 0, stream>>>(x, Wq, Wk, Wv, Wo,
                                         xb, wqt, wkt, wvt, wot);

    dim3 gQKV(INNER / GN, M / GM, 3);
    gemm64<ushort_t><<<gQKV, 256, 0, stream>>>(
        xb, wqt, wkt, wvt, q, k, vt, nullptr, M, INNER, DD, 1);

    dim3 gATT(64, BB * HH);
    attn_mfma<<<gATT, 256, 0, stream>>>(q, k, vt, lw, opart, lpart);

    combine_kernel<<<CMB_UNITS / 256, 256, 0, stream>>>(opart, lpart, ao);

    dim3 gPRJ(DD / GN, M / GM, 1);
    gemm64<float><<<gPRJ, 256, 0, stream>>>(
        ao, wot, wot, wot, out, out, out, bo, M, DD, INNER, 0);
}